// Round 10
// baseline (878.491 us; speedup 1.0000x reference)
//
#include <hip/hip_runtime.h>
#include <hip/hip_bf16.h>

typedef __hip_bfloat16 bf16;
typedef unsigned short ushort;
typedef __attribute__((ext_vector_type(8))) short short8v;   // 8 bf16 = 4 VGPR
typedef __attribute__((ext_vector_type(4))) float float4v;

__device__ __forceinline__ float b2f(bf16 v){ return __bfloat162float(v); }
__device__ __forceinline__ float sigm(float x){ return 1.0f/(1.0f+__expf(-x)); }
__device__ __forceinline__ float tanhc(float x){
  x = fminf(15.0f, fmaxf(-15.0f, x));
  float e = __expf(2.0f*x);
  return (e-1.0f)/(e+1.0f);
}
__device__ __forceinline__ ushort f2bu(float f){
  bf16 h = __float2bfloat16(f); return *reinterpret_cast<ushort*>(&h);
}
__device__ __forceinline__ float bu2f(ushort u){
  return __uint_as_float(((unsigned)u)<<16);
}
__device__ __forceinline__ short8v ldfrag(const ushort* p){
  return *reinterpret_cast<const short8v*>(p);
}
__device__ __forceinline__ void stage_ld(const ushort* s, uint4& a0, uint4& a1,
                                         uint4& a2, uint4& a3){
  a0 = *reinterpret_cast<const uint4*>(s);
  a1 = *reinterpret_cast<const uint4*>(s+512);
  a2 = *reinterpret_cast<const uint4*>(s+1024);
  a3 = *reinterpret_cast<const uint4*>(s+1536);
}
__device__ __forceinline__ void stage_wr(ushort* d, uint4 a0, uint4 a1,
                                         uint4 a2, uint4 a3){
  *reinterpret_cast<uint4*>(d)      = a0;
  *reinterpret_cast<uint4*>(d+512)  = a1;
  *reinterpret_cast<uint4*>(d+1024) = a2;
  *reinterpret_cast<uint4*>(d+1536) = a3;
}

// ---------------------------------------------------------------------------
// ws layout (float offsets)
// ---------------------------------------------------------------------------
#define WS_SMALL   0          // 262144 f32 small weights
#define WS_FLAG    262144
#define WS_ZROW    262160     // 32 f zeros (64-ushort zero row for halo taps)
#define WS_H       262208     // h,c,m f32 states (h slot legacy-zeroed)
#define WS_C       524352
#define WS_M       786496
#define WS_HNEW    1048640    // 262144 f32 cell output h_new
#define WS_QB16    1310784    // 65536 f = [b][n][32] bf16 zero-padded
#define WS_KHB16   1376320    // 65536
#define WS_KMB16   1441856    // 65536
#define WS_VTH16   1507392    // 131072 f = [b][c][1024] bf16
#define WS_VTM16   1638464    // 131072
#define WS_ZCAT    1769536    // 524288
#define WS_ZWT     2293824    // 16384
#define WS_MW4     2310208    // 36864
#define WS_WAHI    2347072    // 147456 f (294912 bf16, chunk-swizzled)
#define WS_WALO    2494528    // 147456
#define WS_XTHI    2641984    // 1048576
#define WS_XTLO    3690560    // 1048576
#define WS_HTHI    4739136    // 131072
#define WS_HTLO    4870208    // 131072 -> total 5001280 f = 20 MB
// small-weight offsets inside WS_SMALL
#define O_CB    0
#define O_WCI   256
#define O_WCF   65792
#define O_WCO   131328
#define O_QW    196864
#define O_QB    197888
#define O_KW    197904
#define O_KB    198928
#define O_K2W   198944
#define O_K2B   199968
#define O_VW    199984
#define O_VB    204080
#define O_V2W   204144
#define O_V2B   208240
#define O_ZW    208304
#define O_ZB    224688
#define O_MW    224816
#define O_MB    261680

// ---------------------------------------------------------------------------
// dtype probe (f32 vs bf16 input data)
// ---------------------------------------------------------------------------
__global__ void k_probe(const unsigned int* __restrict__ Xu, int* __restrict__ flag){
  __shared__ int cnt;
  if (threadIdx.x == 0) cnt = 0;
  __syncthreads();
  unsigned int u = Xu[threadIdx.x];
  float f = __uint_as_float((u & 0xffffu) << 16);
  int bad = (fabsf(f) <= 1e4f) ? 0 : 1;
  atomicAdd(&cnt, bad);
  __syncthreads();
  if (threadIdx.x == 0) *flag = (cnt > 16) ? 1 : 0;
}

// ---------------------------------------------------------------------------
// convert the 18 small inputs into f32 copies in ws
// ---------------------------------------------------------------------------
struct P18 { const void* p[18]; };

__global__ __launch_bounds__(256) void k_wconv(P18 pk, const int* __restrict__ flagp,
                                               float* __restrict__ dst){
  const int ns[18]   = {256,65536,65536,65536,1024,16,1024,16,1024,16,
                        4096,64,4096,64,16384,128,36864,192};
  const int offs[18] = {O_CB,O_WCI,O_WCF,O_WCO,O_QW,O_QB,O_KW,O_KB,O_K2W,O_K2B,
                        O_VW,O_VB,O_V2W,O_V2B,O_ZW,O_ZB,O_MW,O_MB};
  int y = blockIdx.y;
  int n = ns[y];
  int flag = *flagp;
  const void* src = pk.p[y];
  for (int i = blockIdx.x*256 + threadIdx.x; i < n; i += gridDim.x*256){
    float v = flag ? ((const float*)src)[i] : b2f(((const bf16*)src)[i]);
    dst[offs[y] + i] = v;
  }
}

// transpose z_w into [k][r]; pack m_w into mw4[(k4*192 + r)*4 + q]
__global__ __launch_bounds__(256) void k_wtrans(float* __restrict__ ws){
  int i = blockIdx.x*256 + threadIdx.x;
  if (i < 16384){
    int k = i >> 7, r = i & 127;
    ws[WS_ZWT + k*128 + r] = ws[O_ZW + r*128 + k];
  }
  if (i < 36864){
    int q = i & 3; int rest = i >> 2; int r = rest % 192; int k4 = rest / 192;
    ws[WS_MW4 + i] = ws[O_MW + r*192 + k4*4 + q];
  }
}

// ---------------------------------------------------------------------------
// init: zero h,c,m + hT + zrow; build MFMA weight layout wA (hi/lo),
// CHUNK-SWIZZLED: 16B-chunk c of row m stored at chunk (c ^ (m&7)).
// ---------------------------------------------------------------------------
__global__ __launch_bounds__(256) void k_init(const void* __restrict__ conv_w,
                                              const int* __restrict__ flagp,
                                              float* __restrict__ ws){
  int i = blockIdx.x*256 + threadIdx.x;
  int flag = *flagp;
  if (i < 786432) ws[WS_H + i] = 0.0f;
  if (i < 32) ws[WS_ZROW + i] = 0.0f;
  if (i < 294912){
    int ci = i & 127;
    int j = i >> 7;           // j = p*256 + mm
    int mm = j & 255, p = j >> 8;
    int cc = mm >> 2, g = mm & 3;
    int si = ((g*64 + cc)*128 + ci)*9 + p;
    int cis = ((((ci >> 3) ^ (mm & 7)) << 3) | (ci & 7));
    int di = (j << 7) + cis;
    ushort* wah = (ushort*)(ws + WS_WAHI);
    ushort* wal = (ushort*)(ws + WS_WALO);
    if (flag){
      float f = ((const float*)conv_w)[si];
      ushort hi = f2bu(f);
      wah[di] = hi;
      wal[di] = f2bu(f - bu2f(hi));
    } else {
      wah[di] = ((const ushort*)conv_w)[si];
    }
  }
  if (i < 131072){
    ((unsigned*)(ws + WS_HTHI))[i] = 0u;
    ((unsigned*)(ws + WS_HTLO))[i] = 0u;
  }
}

// ---------------------------------------------------------------------------
// X transpose: XT[b][t][px][ci]
// ---------------------------------------------------------------------------
__global__ __launch_bounds__(256) void k_xt(const void* __restrict__ Xraw,
                                            const int* __restrict__ flagp,
                                            float* __restrict__ ws){
  __shared__ ushort hi_s[64][66];
  __shared__ ushort lo_s[64][66];
  int pt = blockIdx.x, s = blockIdx.y;
  int b = s >> 3, t = s & 7;
  int flag = *flagp;
  int tid = threadIdx.x;
  for (int k = 0; k < 16; ++k){
    int idx = tid + k*256;
    int ci = idx >> 6, pxl = idx & 63;
    size_t si = ((size_t)(b*64 + ci)*8 + t)*1024 + pt*64 + pxl;
    if (flag){
      float f = ((const float*)Xraw)[si];
      ushort h = f2bu(f);
      hi_s[pxl][ci] = h;
      lo_s[pxl][ci] = f2bu(f - bu2f(h));
    } else {
      hi_s[pxl][ci] = ((const ushort*)Xraw)[si];
    }
  }
  __syncthreads();
  ushort* xh = (ushort*)(ws + WS_XTHI) + ((size_t)s*1024 + pt*64)*64;
  ushort* xl = (ushort*)(ws + WS_XTLO) + ((size_t)s*1024 + pt*64)*64;
  for (int k = 0; k < 16; ++k){
    int idx = tid + k*256;
    int pxl = idx >> 6, ci = idx & 63;
    xh[pxl*64 + ci] = hi_s[pxl][ci];
    if (flag) xl[pxl*64 + ci] = lo_s[pxl][ci];
  }
}

// ---------------------------------------------------------------------------
// conv 3x3 + peephole LSTM via MFMA implicit GEMM.
// grid (64 nt, 2 mh, 4 b) = 512 blocks (2/CU), block 512 = 8 waves.
// Wave w owns 16 m-rows (mh*128 + w*16) x 16 px; acc = 4 VGPRs.
// A staged reg->LDS (T14): 64KB double buffer, 32KB p-slice; stage(p+1)
// loads issued at loop top, ds_writes after MFMAs; barrier per p.
// A chunks XOR-swizzled (c^=row&7, baked into wa layout) -> 2-way banks.
// B (X/h hi/lo) read direct from global with zero-row pointer select.
// ---------------------------------------------------------------------------
__global__ __launch_bounds__(512, 4) void k_conv_mfma(
  const int* __restrict__ flagp,
  const ushort* __restrict__ wa_hi, const ushort* __restrict__ wa_lo,
  const ushort* __restrict__ xt_hi, const ushort* __restrict__ xt_lo,
  const ushort* __restrict__ ht_hi, const ushort* __restrict__ ht_lo,
  const ushort* __restrict__ zrow,
  const float* __restrict__ smalls, float* __restrict__ cst,
  float* __restrict__ hnew, int t)
{
  __shared__ ushort albuf[32768];    // 64 KB = 2 x 32KB A p-slices
  int nt = blockIdx.x, mh = blockIdx.y, b = blockIdx.z;
  int tid = threadIdx.x;
  int flag = *flagp;
  int w = tid >> 6, lane = tid & 63, lr = lane & 15, lk = lane >> 4;
  int px = nt*16 + lr, y = px >> 5, x = px & 31;

  const ushort* xb  = xt_hi + ((size_t)(b*8 + t))*65536;
  const ushort* xlb = xt_lo + ((size_t)(b*8 + t))*65536;
  const ushort* hb  = ht_hi + (size_t)b*65536;
  const ushort* hlb = ht_lo + (size_t)b*65536;

  const int sgo = w*2048 + lane*8;                      // stage offset in slice
  const ushort* aslice = wa_hi + (size_t)mh*16384 + sgo; // + p*32768
  const ushort* lslice = wa_lo + (size_t)mh*16384 + sgo;
  const int arow = (w*16 + lr)*128;
  const int sw = lr & 7;
  const int c0 = ((( 0+lk) ^ sw) << 3);
  const int c1 = ((( 4+lk) ^ sw) << 3);
  const int c2 = ((( 8+lk) ^ sw) << 3);
  const int c3 = (((12+lk) ^ sw) << 3);

  float4v acc = {0.f,0.f,0.f,0.f};

  if (!flag){
    // ---------------- bf16 path: double-buffered T14 staging ----------------
    uint4 s0,s1,s2,s3;
    stage_ld(aslice, s0,s1,s2,s3);
    stage_wr(albuf + sgo, s0,s1,s2,s3);
    __syncthreads();
    #pragma unroll
    for (int p = 0; p < 9; ++p){
      if (p < 8) stage_ld(aslice + (size_t)(p+1)*32768, s0,s1,s2,s3);
      const ushort* ab = albuf + (p&1)*16384;
      short8v A0 = ldfrag(ab + arow + c0);
      short8v A1 = ldfrag(ab + arow + c1);
      short8v A2 = ldfrag(ab + arow + c2);
      short8v A3 = ldfrag(ab + arow + c3);
      int dy = p/3 - 1, dxx = p%3 - 1;
      int py = y + dy, xx = x + dxx;
      bool valid = (py >= 0) & (py < 32) & (xx >= 0) & (xx < 32);
      size_t pin = (size_t)(valid ? (py*32 + xx) : 0) * 64;
      const ushort* bpx = valid ? xb  + pin : zrow;
      const ushort* bph = valid ? hb  + pin : zrow;
      const ushort* bpl = valid ? hlb + pin : zrow;
      short8v BX0 = ldfrag(bpx + lk*8), BX1 = ldfrag(bpx + lk*8 + 32);
      short8v BH0 = ldfrag(bph + lk*8), BH1 = ldfrag(bph + lk*8 + 32);
      short8v BL0 = ldfrag(bpl + lk*8), BL1 = ldfrag(bpl + lk*8 + 32);
      acc = __builtin_amdgcn_mfma_f32_16x16x32_bf16(A0, BX0, acc, 0,0,0);
      acc = __builtin_amdgcn_mfma_f32_16x16x32_bf16(A1, BX1, acc, 0,0,0);
      acc = __builtin_amdgcn_mfma_f32_16x16x32_bf16(A2, BH0, acc, 0,0,0);
      acc = __builtin_amdgcn_mfma_f32_16x16x32_bf16(A3, BH1, acc, 0,0,0);
      acc = __builtin_amdgcn_mfma_f32_16x16x32_bf16(A2, BL0, acc, 0,0,0);
      acc = __builtin_amdgcn_mfma_f32_16x16x32_bf16(A3, BL1, acc, 0,0,0);
      if (p < 8) stage_wr(albuf + ((p+1)&1)*16384 + sgo, s0,s1,s2,s3);
      __syncthreads();
    }
  } else {
    // ---------------- f32 path (cold): single-buffered hi+lo ----------------
    #pragma unroll 1
    for (int p = 0; p < 9; ++p){
      uint4 h0,h1,h2,h3, l0,l1,l2,l3;
      stage_ld(aslice + (size_t)p*32768, h0,h1,h2,h3);
      stage_ld(lslice + (size_t)p*32768, l0,l1,l2,l3);
      __syncthreads();
      stage_wr(albuf + sgo, h0,h1,h2,h3);
      stage_wr(albuf + 16384 + sgo, l0,l1,l2,l3);
      __syncthreads();
      short8v A0 = ldfrag(albuf + arow + c0);
      short8v A1 = ldfrag(albuf + arow + c1);
      short8v A2 = ldfrag(albuf + arow + c2);
      short8v A3 = ldfrag(albuf + arow + c3);
      short8v Al0 = ldfrag(albuf + 16384 + arow + c0);
      short8v Al1 = ldfrag(albuf + 16384 + arow + c1);
      short8v Al2 = ldfrag(albuf + 16384 + arow + c2);
      short8v Al3 = ldfrag(albuf + 16384 + arow + c3);
      int dy = p/3 - 1, dxx = p%3 - 1;
      int py = y + dy, xx = x + dxx;
      bool valid = (py >= 0) & (py < 32) & (xx >= 0) & (xx < 32);
      size_t pin = (size_t)(valid ? (py*32 + xx) : 0) * 64;
      const ushort* bpx  = valid ? xb  + pin : zrow;
      const ushort* bph  = valid ? hb  + pin : zrow;
      const ushort* bpl  = valid ? hlb + pin : zrow;
      const ushort* bpxl = valid ? xlb + pin : zrow;
      short8v BX0 = ldfrag(bpx + lk*8),  BX1 = ldfrag(bpx + lk*8 + 32);
      short8v BH0 = ldfrag(bph + lk*8),  BH1 = ldfrag(bph + lk*8 + 32);
      short8v BL0 = ldfrag(bpl + lk*8),  BL1 = ldfrag(bpl + lk*8 + 32);
      short8v BXl0 = ldfrag(bpxl + lk*8), BXl1 = ldfrag(bpxl + lk*8 + 32);
      acc = __builtin_amdgcn_mfma_f32_16x16x32_bf16(A0, BX0, acc, 0,0,0);
      acc = __builtin_amdgcn_mfma_f32_16x16x32_bf16(A1, BX1, acc, 0,0,0);
      acc = __builtin_amdgcn_mfma_f32_16x16x32_bf16(A2, BH0, acc, 0,0,0);
      acc = __builtin_amdgcn_mfma_f32_16x16x32_bf16(A3, BH1, acc, 0,0,0);
      acc = __builtin_amdgcn_mfma_f32_16x16x32_bf16(A2, BL0, acc, 0,0,0);
      acc = __builtin_amdgcn_mfma_f32_16x16x32_bf16(A3, BL1, acc, 0,0,0);
      acc = __builtin_amdgcn_mfma_f32_16x16x32_bf16(A0, BXl0, acc, 0,0,0);
      acc = __builtin_amdgcn_mfma_f32_16x16x32_bf16(A1, BXl1, acc, 0,0,0);
      acc = __builtin_amdgcn_mfma_f32_16x16x32_bf16(Al0, BX0, acc, 0,0,0);
      acc = __builtin_amdgcn_mfma_f32_16x16x32_bf16(Al1, BX1, acc, 0,0,0);
      acc = __builtin_amdgcn_mfma_f32_16x16x32_bf16(Al2, BH0, acc, 0,0,0);
      acc = __builtin_amdgcn_mfma_f32_16x16x32_bf16(Al3, BH1, acc, 0,0,0);
      __syncthreads();
    }
  }

  // epilogue: cc = mh*32 + w*4 + lk, gate = acc reg
  {
    int cc = mh*32 + w*4 + lk;
    int wi = cc*1024 + px;
    size_t sidx = ((size_t)(b*64 + cc))*1024 + px;
    float cprev = cst[sidx];
    float ic = acc[0] + smalls[O_CB + cc];
    float fc = acc[1] + smalls[O_CB + 64 + cc];
    float gc = acc[2] + smalls[O_CB + 128 + cc];
    float oc = acc[3] + smalls[O_CB + 192 + cc];
    float ig = sigm(ic + smalls[O_WCI + wi]*cprev);
    float fg = sigm(fc + smalls[O_WCF + wi]*cprev);
    float cnew = fg*cprev + ig*tanhc(gc);
    float og = sigm(oc + smalls[O_WCO + wi]*cnew);
    cst[sidx]  = cnew;
    hnew[sidx] = og*tanhc(cnew);
  }
}

// ---------------------------------------------------------------------------
// 1x1 projections -> bf16 MFMA-ready buffers.
// grid (128 ntiles of 8, 4 b) = 512 blocks (2/CU), block 256
// ---------------------------------------------------------------------------
__global__ __launch_bounds__(256) void k_proj(
  const float* __restrict__ hnew, const float* __restrict__ mst,
  const float* __restrict__ smalls,
  ushort* __restrict__ qb16, ushort* __restrict__ khb16, ushort* __restrict__ kmb16,
  ushort* __restrict__ vth16, ushort* __restrict__ vtm16)
{
  __shared__ float hs[64*9];
  __shared__ float ms[64*9];
  int b = blockIdx.y, n0 = blockIdx.x*8;
  int tid = threadIdx.x, nl = tid&7, rg = tid>>3;
  for (int idx = tid; idx < 512; idx += 256){
    int nn = idx & 7, ch = idx >> 3;
    hs[ch*9+nn] = hnew[((size_t)b*64+ch)*1024 + n0 + nn];
    ms[ch*9+nn] = mst [((size_t)b*64+ch)*1024 + n0 + nn];
  }
  __syncthreads();
  int n = n0 + nl;
  for (int j = 0; j < 6; ++j){
    int r = rg + 32*j;
    if (r >= 176) break;
    const float* src; const float* wrow; float bias;
    int mode, rr;
    if (r < 16)      { mode=0; rr=r;     src = hs; wrow = smalls+O_QW  + rr*64; bias = smalls[O_QB+rr]; }
    else if (r < 32) { mode=1; rr=r-16;  src = hs; wrow = smalls+O_KW  + rr*64; bias = smalls[O_KB+rr]; }
    else if (r < 48) { mode=2; rr=r-32;  src = ms; wrow = smalls+O_K2W + rr*64; bias = smalls[O_K2B+rr]; }
    else if (r < 112){ mode=3; rr=r-48;  src = hs; wrow = smalls+O_VW  + rr*64; bias = smalls[O_VB+rr]; }
    else             { mode=4; rr=r-112; src = ms; wrow = smalls+O_V2W + rr*64; bias = smalls[O_V2B+rr]; }
    float acc = bias;
    #pragma unroll
    for (int c4 = 0; c4 < 16; ++c4){
      float4 w4 = *reinterpret_cast<const float4*>(wrow + c4*4);
      acc += w4.x*src[(c4*4+0)*9+nl] + w4.y*src[(c4*4+1)*9+nl]
           + w4.z*src[(c4*4+2)*9+nl] + w4.w*src[(c4*4+3)*9+nl];
    }
    ushort v = f2bu(acc);
    if (mode <= 2){
      ushort* base = (mode==0) ? qb16 : (mode==1) ? khb16 : kmb16;
      size_t o = ((size_t)b*1024 + n)*32;
      base[o + rr] = v;
      base[o + 16 + rr] = 0;
    } else {
      ushort* base = (mode==3) ? vth16 : vtm16;
      base[((size_t)b*64 + rr)*1024 + n] = v;
    }
  }
}

// ---------------------------------------------------------------------------
// MFMA flash attention. grid (64 ntiles of 16, 4 b, 2 br) = 512 blocks (2/CU),
// block 256 = 4 waves.
// ---------------------------------------------------------------------------
__global__ __launch_bounds__(256) void k_fatt(
  const ushort* __restrict__ qb16, const ushort* __restrict__ khb16,
  const ushort* __restrict__ kmb16, const ushort* __restrict__ vth16,
  const ushort* __restrict__ vtm16, float* __restrict__ zcat)
{
  __shared__ ushort es[16*272];
  __shared__ float rs_s[4][16];
  int n0 = blockIdx.x*16, b = blockIdx.y, br = blockIdx.z;
  const ushort* kb = (br ? kmb16 : khb16) + (size_t)b*32768;
  const ushort* vt = (br ? vtm16 : vth16) + (size_t)b*65536;
  const ushort* qp = qb16 + (size_t)b*32768;
  int tid = threadIdx.x;
  int w = tid >> 6, lane = tid & 63, lr = lane & 15, lk = lane >> 4;
  const float4v Z4 = {0.f,0.f,0.f,0.f};

  short8v qf = ldfrag(qp + (size_t)(n0 + lr)*32 + lk*8);

  float4v acc[2];
  acc[0]=Z4; acc[1]=Z4;
  float rsum = 0.f;

  #pragma unroll 1
  for (int mc = 0; mc < 4; ++mc){
    int mbase = mc*256 + w*64;
    #pragma unroll
    for (int tau = 0; tau < 4; ++tau){
      short8v af = ldfrag(kb + (size_t)(mbase + tau*16 + lr)*32 + lk*8);
      float4v d = __builtin_amdgcn_mfma_f32_16x16x32_bf16(af, qf, Z4, 0,0,0);
      ushort u0 = f2bu(__expf(fminf(d[0], 60.f)));
      ushort u1 = f2bu(__expf(fminf(d[1], 60.f)));
      ushort u2 = f2bu(__expf(fminf(d[2], 60.f)));
      ushort u3 = f2bu(__expf(fminf(d[3], 60.f)));
      rsum += (bu2f(u0) + bu2f(u1)) + (bu2f(u2) + bu2f(u3));
      unsigned lo = (unsigned)u0 | ((unsigned)u1 << 16);
      unsigned hi = (unsigned)u2 | ((unsigned)u3 << 16);
      *reinterpret_cast<uint2*>(&es[lr*272 + w*64 + tau*16 + lk*4]) = make_uint2(lo, hi);
    }
    __syncthreads();
    #pragma unroll
    for (int ks = 0; ks < 8; ++ks){
      short8v av = ldfrag(vt + (size_t)(w*16 + lr)*1024 + mc*256 + ks*32 + lk*8);
      short8v bv = ldfrag(&es[lr*272 + ks*32 + lk*8]);
      acc[ks & 1] = __builtin_amdgcn_mfma_f32_16x16x32_bf16(av, bv, acc[ks & 1], 0,0,0);
    }
    __syncthreads();
  }

  {
    float r = rsum;
    r += __shfl_xor(r, 16);
    r += __shfl_xor(r, 32);
    if (lane < 16) rs_s[w][lr] = r;
  }
  __syncthreads();
  {
    float rinv = 1.0f / (rs_s[0][lr] + rs_s[1][lr] + rs_s[2][lr] + rs_s[3][lr]);
    #pragma unroll
    for (int r = 0; r < 4; ++r){
      int c = w*16 + lk*4 + r;
      zcat[((size_t)(b*128 + br*64 + c))*1024 + n0 + lr] = (acc[0][r] + acc[1][r])*rinv;
    }
  }
}

// ---------------------------------------------------------------------------
// zcomb: zt = zwT^T@zcat+z_b; comb = mw4@[zt;hnew]+m_b; gate; h_out
// writes m state, hT_hi/lo bf16, and d_out
// ---------------------------------------------------------------------------
__global__ __launch_bounds__(256) void k_zcomb(
  const float* __restrict__ zcat, const float* __restrict__ hnew,
  const float* __restrict__ smalls, const float* __restrict__ zwT,
  const float* __restrict__ mw4, const int* __restrict__ flagp,
  float* __restrict__ mst, ushort* __restrict__ hth, ushort* __restrict__ htl,
  void* __restrict__ outraw, int t)
{
  __shared__ float zin[128*9];
  __shared__ float hl [64*9];
  __shared__ float ml [64*9];
  __shared__ float zt_s[8*132];
  __shared__ float ho_s[64*9];
  __shared__ float mn_s[64*9];
  int n0 = blockIdx.x*8, b = blockIdx.y;
  int tid = threadIdx.x;
  int px = tid >> 5, lr = tid & 31;
  int flag = *flagp;
  for (int idx = tid; idx < 1024; idx += 256){
    int ch = idx >> 3, pp = idx & 7;
    zin[ch*9+pp] = zcat[((size_t)b*128 + ch)*1024 + n0 + pp];
  }
  for (int idx = tid; idx < 512; idx += 256){
    int ch = idx >> 3, pp = idx & 7;
    hl[ch*9+pp] = hnew[((size_t)b*64 + ch)*1024 + n0 + pp];
    ml[ch*9+pp] = mst [((size_t)b*64 + ch)*1024 + n0 + pp];
  }
  __syncthreads();
  {
    float4 a4 = *reinterpret_cast<const float4*>(&smalls[O_ZB + lr*4]);
    float acc0=a4.x, acc1=a4.y, acc2=a4.z, acc3=a4.w;
    #pragma unroll 4
    for (int k = 0; k < 128; ++k){
      float zv = zin[k*9 + px];
      float4 w4 = *reinterpret_cast<const float4*>(&zwT[k*128 + lr*4]);
      acc0 += w4.x*zv; acc1 += w4.y*zv; acc2 += w4.z*zv; acc3 += w4.w*zv;
    }
    *reinterpret_cast<float4*>(&zt_s[px*132 + lr*4]) = make_float4(acc0,acc1,acc2,acc3);
  }
  __syncthreads();
  {
    float acc6[6];
    #pragma unroll
    for (int i=0;i<6;++i) acc6[i] = smalls[O_MB + lr + 32*i];
    #pragma unroll 2
    for (int k4 = 0; k4 < 32; ++k4){
      float4 xv = *reinterpret_cast<const float4*>(&zt_s[px*132 + k4*4]);
      const float* wb = mw4 + (size_t)(k4*192)*4;
      #pragma unroll
      for (int i=0;i<6;++i){
        float4 w = *reinterpret_cast<const float4*>(&wb[(lr + 32*i)*4]);
        acc6[i] += w.x*xv.x + w.y*xv.y + w.z*xv.z + w.w*xv.w;
      }
    }
    #pragma unroll 2
    for (int k4 = 32; k4 < 48; ++k4){
      int ch = (k4-32)*4;
      float4 xv = make_float4(hl[ch*9+px], hl[(ch+1)*9+px], hl[(ch+2)*9+px], hl[(ch+3)*9+px]);
      const float* wb = mw4 + (size_t)(k4*192)*4;
      #pragma unroll
      for (int i=0;i<6;++i){
        float4 w = *reinterpret_cast<const float4*>(&wb[(lr + 32*i)*4]);
        acc6[i] += w.x*xv.x + w.y*xv.y + w.z*xv.z + w.w*xv.w;
      }
    }
    #pragma unroll
    for (int j=0;j<2;++j){
      int ch = lr + 32*j;
      float mold = ml[ch*9 + px];
      float gi = sigm(acc6[4+j]);
      float mnew = (1.0f-gi)*mold + gi*tanhc(acc6[2+j]);
      float ho = sigm(acc6[j])*mnew;
      ho_s[ch*9+px] = ho;
      mn_s[ch*9+px] = mnew;
    }
  }
  __syncthreads();
  for (int idx = tid; idx < 512; idx += 256){
    int ch = idx >> 3, pp = idx & 7;
    int n = n0 + pp;
    size_t gidx = ((size_t)b*64 + ch)*1024 + n;
    mst[gidx] = mn_s[ch*9+pp];
    float ho = ho_s[ch*9+pp];
    size_t tix = ((size_t)b*1024 + n)*64 + ch;
    ushort hb_ = f2bu(ho);
    hth[tix] = hb_;
    htl[tix] = f2bu(ho - bu2f(hb_));
    size_t oidx = ((size_t)(b*64+ch)*8 + t)*1024 + n;
    if (flag) ((float*)outraw)[oidx] = ho;
    else      ((bf16*)outraw)[oidx] = __float2bfloat16(ho);
  }
}

extern "C" void kernel_launch(void* const* d_in, const int* in_sizes, int n_in,
                              void* d_out, int out_size, void* d_ws, size_t ws_size,
                              hipStream_t stream)
{
  float* ws = (float*)d_ws;
  int* flag = (int*)(ws + WS_FLAG);
  float* c    = ws + WS_C;
  float* m    = ws + WS_M;
  float* hnew = ws + WS_HNEW;
  float* zcat = ws + WS_ZCAT;
  float* zwT  = ws + WS_ZWT;
  float* mw4  = ws + WS_MW4;
  ushort* zrow  = (ushort*)(ws + WS_ZROW);
  ushort* qb16  = (ushort*)(ws + WS_QB16);
  ushort* khb16 = (ushort*)(ws + WS_KHB16);
  ushort* kmb16 = (ushort*)(ws + WS_KMB16);
  ushort* vth16 = (ushort*)(ws + WS_VTH16);
  ushort* vtm16 = (ushort*)(ws + WS_VTM16);
  ushort* wa_hi = (ushort*)(ws + WS_WAHI);
  ushort* wa_lo = (ushort*)(ws + WS_WALO);
  ushort* xt_hi = (ushort*)(ws + WS_XTHI);
  ushort* xt_lo = (ushort*)(ws + WS_XTLO);
  ushort* ht_hi = (ushort*)(ws + WS_HTHI);
  ushort* ht_lo = (ushort*)(ws + WS_HTLO);

  k_probe<<<1, 256, 0, stream>>>((const unsigned int*)d_in[0], flag);
  P18 pk;
  for (int i = 0; i < 18; ++i) pk.p[i] = d_in[2 + i];
  k_wconv<<<dim3(64,18), 256, 0, stream>>>(pk, flag, ws);
  k_init<<<3072, 256, 0, stream>>>(d_in[1], flag, ws);
  k_xt<<<dim3(16,32), 256, 0, stream>>>(d_in[0], flag, ws);
  k_wtrans<<<144, 256, 0, stream>>>(ws);

  for (int t = 0; t < 8; ++t){
    k_conv_mfma<<<dim3(64,2,4), 512, 0, stream>>>(flag, wa_hi, wa_lo, xt_hi, xt_lo,
                                                  ht_hi, ht_lo, zrow, ws, c, hnew, t);
    k_proj<<<dim3(128,4), 256, 0, stream>>>(hnew, m, ws, qb16, khb16, kmb16, vth16, vtm16);
    k_fatt<<<dim3(64,4,2), 256, 0, stream>>>(qb16, khb16, kmb16, vth16, vtm16, zcat);
    k_zcomb<<<dim3(128,4), 256, 0, stream>>>(zcat, hnew, ws, zwT, mw4, flag,
                                             m, ht_hi, ht_lo, d_out, t);
  }
  (void)in_sizes; (void)n_in; (void)out_size; (void)ws_size;
}

// Round 11
// 708.649 us; speedup vs baseline: 1.2397x; 1.2397x over previous
//
#include <hip/hip_runtime.h>
#include <hip/hip_bf16.h>

typedef __hip_bfloat16 bf16;
typedef unsigned short ushort;
typedef __attribute__((ext_vector_type(8))) short short8v;   // 8 bf16 = 4 VGPR
typedef __attribute__((ext_vector_type(4))) float float4v;

__device__ __forceinline__ float b2f(bf16 v){ return __bfloat162float(v); }
__device__ __forceinline__ float sigm(float x){ return 1.0f/(1.0f+__expf(-x)); }
__device__ __forceinline__ float tanhc(float x){
  x = fminf(15.0f, fmaxf(-15.0f, x));
  float e = __expf(2.0f*x);
  return (e-1.0f)/(e+1.0f);
}
__device__ __forceinline__ ushort f2bu(float f){
  bf16 h = __float2bfloat16(f); return *reinterpret_cast<ushort*>(&h);
}
__device__ __forceinline__ float bu2f(ushort u){
  return __uint_as_float(((unsigned)u)<<16);
}
__device__ __forceinline__ short8v ldfrag(const ushort* p){
  return *reinterpret_cast<const short8v*>(p);
}
// direct global->LDS DMA, 16B per lane; lds dst = uniform base + lane*16
__device__ __forceinline__ void glds16(const ushort* g, ushort* l){
  __builtin_amdgcn_global_load_lds(
    (const __attribute__((address_space(1))) unsigned int*)g,
    (__attribute__((address_space(3))) unsigned int*)l, 16, 0, 0);
}
__device__ __forceinline__ void stage_ld(const ushort* s, uint4& a0, uint4& a1,
                                         uint4& a2, uint4& a3){
  a0 = *reinterpret_cast<const uint4*>(s);
  a1 = *reinterpret_cast<const uint4*>(s+512);
  a2 = *reinterpret_cast<const uint4*>(s+1024);
  a3 = *reinterpret_cast<const uint4*>(s+1536);
}
__device__ __forceinline__ void stage_wr(ushort* d, uint4 a0, uint4 a1,
                                         uint4 a2, uint4 a3){
  *reinterpret_cast<uint4*>(d)      = a0;
  *reinterpret_cast<uint4*>(d+512)  = a1;
  *reinterpret_cast<uint4*>(d+1024) = a2;
  *reinterpret_cast<uint4*>(d+1536) = a3;
}

// ---------------------------------------------------------------------------
// ws layout (float offsets)
// ---------------------------------------------------------------------------
#define WS_SMALL   0          // 262144 f32 small weights
#define WS_FLAG    262144
#define WS_ZROW    262160     // 32 f zeros (legacy, unused)
#define WS_H       262208     // h,c,m f32 states (h slot legacy-zeroed)
#define WS_C       524352
#define WS_M       786496
#define WS_HNEW    1048640    // 262144 f32 cell output h_new
#define WS_QB16    1310784    // 65536 f = [b][n][32] bf16 zero-padded
#define WS_KHB16   1376320    // 65536
#define WS_KMB16   1441856    // 65536
#define WS_VTH16   1507392    // 131072 f = [b][c][1024] bf16
#define WS_VTM16   1638464    // 131072
#define WS_ZCAT    1769536    // 524288
#define WS_ZWT     2293824    // 16384
#define WS_MW4     2310208    // 36864
#define WS_WAHI    2347072    // 147456 f (294912 bf16, chunk-swizzled)
#define WS_WALO    2494528    // 147456
#define WS_XTHI    2641984    // 1048576
#define WS_XTLO    3690560    // 1048576
#define WS_HTHI    4739136    // 131072
#define WS_HTLO    4870208    // 131072 -> total 5001280 f = 20 MB
// small-weight offsets inside WS_SMALL
#define O_CB    0
#define O_WCI   256
#define O_WCF   65792
#define O_WCO   131328
#define O_QW    196864
#define O_QB    197888
#define O_KW    197904
#define O_KB    198928
#define O_K2W   198944
#define O_K2B   199968
#define O_VW    199984
#define O_VB    204080
#define O_V2W   204144
#define O_V2B   208240
#define O_ZW    208304
#define O_ZB    224688
#define O_MW    224816
#define O_MB    261680

// ---------------------------------------------------------------------------
// dtype probe (f32 vs bf16 input data)
// ---------------------------------------------------------------------------
__global__ void k_probe(const unsigned int* __restrict__ Xu, int* __restrict__ flag){
  __shared__ int cnt;
  if (threadIdx.x == 0) cnt = 0;
  __syncthreads();
  unsigned int u = Xu[threadIdx.x];
  float f = __uint_as_float((u & 0xffffu) << 16);
  int bad = (fabsf(f) <= 1e4f) ? 0 : 1;
  atomicAdd(&cnt, bad);
  __syncthreads();
  if (threadIdx.x == 0) *flag = (cnt > 16) ? 1 : 0;
}

// ---------------------------------------------------------------------------
// convert the 18 small inputs into f32 copies in ws
// ---------------------------------------------------------------------------
struct P18 { const void* p[18]; };

__global__ __launch_bounds__(256) void k_wconv(P18 pk, const int* __restrict__ flagp,
                                               float* __restrict__ dst){
  const int ns[18]   = {256,65536,65536,65536,1024,16,1024,16,1024,16,
                        4096,64,4096,64,16384,128,36864,192};
  const int offs[18] = {O_CB,O_WCI,O_WCF,O_WCO,O_QW,O_QB,O_KW,O_KB,O_K2W,O_K2B,
                        O_VW,O_VB,O_V2W,O_V2B,O_ZW,O_ZB,O_MW,O_MB};
  int y = blockIdx.y;
  int n = ns[y];
  int flag = *flagp;
  const void* src = pk.p[y];
  for (int i = blockIdx.x*256 + threadIdx.x; i < n; i += gridDim.x*256){
    float v = flag ? ((const float*)src)[i] : b2f(((const bf16*)src)[i]);
    dst[offs[y] + i] = v;
  }
}

// transpose z_w into [k][r]; pack m_w into mw4[(k4*192 + r)*4 + q]
__global__ __launch_bounds__(256) void k_wtrans(float* __restrict__ ws){
  int i = blockIdx.x*256 + threadIdx.x;
  if (i < 16384){
    int k = i >> 7, r = i & 127;
    ws[WS_ZWT + k*128 + r] = ws[O_ZW + r*128 + k];
  }
  if (i < 36864){
    int q = i & 3; int rest = i >> 2; int r = rest % 192; int k4 = rest / 192;
    ws[WS_MW4 + i] = ws[O_MW + r*192 + k4*4 + q];
  }
}

// ---------------------------------------------------------------------------
// init: zero h,c,m + hT + zrow; build MFMA weight layout wA (hi/lo),
// CHUNK-SWIZZLED: 16B-chunk c of row m stored at chunk (c ^ (m&7)).
// ---------------------------------------------------------------------------
__global__ __launch_bounds__(256) void k_init(const void* __restrict__ conv_w,
                                              const int* __restrict__ flagp,
                                              float* __restrict__ ws){
  int i = blockIdx.x*256 + threadIdx.x;
  int flag = *flagp;
  if (i < 786432) ws[WS_H + i] = 0.0f;
  if (i < 32) ws[WS_ZROW + i] = 0.0f;
  if (i < 294912){
    int ci = i & 127;
    int j = i >> 7;           // j = p*256 + mm
    int mm = j & 255, p = j >> 8;
    int cc = mm >> 2, g = mm & 3;
    int si = ((g*64 + cc)*128 + ci)*9 + p;
    int cis = ((((ci >> 3) ^ (mm & 7)) << 3) | (ci & 7));
    int di = (j << 7) + cis;
    ushort* wah = (ushort*)(ws + WS_WAHI);
    ushort* wal = (ushort*)(ws + WS_WALO);
    if (flag){
      float f = ((const float*)conv_w)[si];
      ushort hi = f2bu(f);
      wah[di] = hi;
      wal[di] = f2bu(f - bu2f(hi));
    } else {
      wah[di] = ((const ushort*)conv_w)[si];
    }
  }
  if (i < 131072){
    ((unsigned*)(ws + WS_HTHI))[i] = 0u;
    ((unsigned*)(ws + WS_HTLO))[i] = 0u;
  }
}

// ---------------------------------------------------------------------------
// X transpose: XT[b][t][px][ci]
// ---------------------------------------------------------------------------
__global__ __launch_bounds__(256) void k_xt(const void* __restrict__ Xraw,
                                            const int* __restrict__ flagp,
                                            float* __restrict__ ws){
  __shared__ ushort hi_s[64][66];
  __shared__ ushort lo_s[64][66];
  int pt = blockIdx.x, s = blockIdx.y;
  int b = s >> 3, t = s & 7;
  int flag = *flagp;
  int tid = threadIdx.x;
  for (int k = 0; k < 16; ++k){
    int idx = tid + k*256;
    int ci = idx >> 6, pxl = idx & 63;
    size_t si = ((size_t)(b*64 + ci)*8 + t)*1024 + pt*64 + pxl;
    if (flag){
      float f = ((const float*)Xraw)[si];
      ushort h = f2bu(f);
      hi_s[pxl][ci] = h;
      lo_s[pxl][ci] = f2bu(f - bu2f(h));
    } else {
      hi_s[pxl][ci] = ((const ushort*)Xraw)[si];
    }
  }
  __syncthreads();
  ushort* xh = (ushort*)(ws + WS_XTHI) + ((size_t)s*1024 + pt*64)*64;
  ushort* xl = (ushort*)(ws + WS_XTLO) + ((size_t)s*1024 + pt*64)*64;
  for (int k = 0; k < 16; ++k){
    int idx = tid + k*256;
    int pxl = idx >> 6, ci = idx & 63;
    xh[pxl*64 + ci] = hi_s[pxl][ci];
    if (flag) xl[pxl*64 + ci] = lo_s[pxl][ci];
  }
}

// ---------------------------------------------------------------------------
// conv 3x3 + peephole LSTM via MFMA implicit GEMM.
// grid (64 nt, 2 mh, 4 b) = 512 blocks (2/CU), block 512 = 8 waves.
// Wave w owns 16 m-rows (mh*128 + w*16) x 16 px; acc = 4 VGPRs.
// B: full 3x18-px halo staged ONCE in LDS (covers all 9 taps, zero-padded).
// A: streamed HBM/L2 -> LDS via global_load_lds width16 into a PRIVATE
//    per-wave 4KB region (wave reads only its own rows -> NO barriers in
//    the p-loop; only an explicit per-wave s_waitcnt vmcnt(0) per p).
// A global layout chunk-swizzled at init (c ^= row&7); ds_read applies the
// same XOR (both-sides rule) -> ~4-way banks on A, B stride 264 free.
// LDS 59.8 KB -> 2 blocks/CU so the other block hides the per-p wait.
// ---------------------------------------------------------------------------
__global__ __launch_bounds__(512, 4) void k_conv_mfma(
  const int* __restrict__ flagp,
  const ushort* __restrict__ wa_hi, const ushort* __restrict__ wa_lo,
  const ushort* __restrict__ xt_hi, const ushort* __restrict__ xt_lo,
  const ushort* __restrict__ ht_hi, const ushort* __restrict__ ht_lo,
  const float* __restrict__ smalls, float* __restrict__ cst,
  float* __restrict__ hnew, int t)
{
  __shared__ ushort albuf[16384];    // 32 KB: 8 wave-private 4KB A slices
  __shared__ ushort bsm[54*264];     // 27.8 KB: B halo (all 9 taps)
  int nt = blockIdx.x, mh = blockIdx.y, b = blockIdx.z;
  int tid = threadIdx.x;
  int flag = *flagp;
  int ytile = nt >> 1, x0 = (nt & 1) * 16;

  const ushort* xb  = xt_hi + ((size_t)(b*8 + t))*65536;
  const ushort* xlb = xt_lo + ((size_t)(b*8 + t))*65536;
  const ushort* hb  = ht_hi + (size_t)b*65536;
  const ushort* hlb = ht_lo + (size_t)b*65536;

  // ---- stage B halo once: 54 slots (3 rows x 18 x) x 32 chunks of 8 ushort
  const uint4 Z16 = make_uint4(0,0,0,0);
  for (int idx = tid; idx < 1728; idx += 512){
    int slot = idx >> 5, c = idx & 31;
    int rr = slot / 18, xi = slot - rr*18;
    int gy = ytile - 1 + rr, gx = x0 - 1 + xi;
    bool valid = (gy >= 0) & (gy < 32) & (gx >= 0) & (gx < 32);
    int px = gy*32 + gx;
    uint4 v = Z16;
    if (valid){
      if (c < 8)       v = *reinterpret_cast<const uint4*>(xb  + (size_t)px*64 + c*8);
      else if (c < 16) v = *reinterpret_cast<const uint4*>(hb  + (size_t)px*64 + (c-8)*8);
      else if (c < 24) v = *reinterpret_cast<const uint4*>(hlb + (size_t)px*64 + (c-16)*8);
      else if (flag)   v = *reinterpret_cast<const uint4*>(xlb + (size_t)px*64 + (c-24)*8);
    }
    *reinterpret_cast<uint4*>(&bsm[slot*264 + c*8]) = v;
  }
  __syncthreads();   // drains vmcnt+lgkmcnt -> exact vmcnt counting below

  int w = tid >> 6, lane = tid & 63, lr = lane & 15, lk = lane >> 4;
  int px = nt*16 + lr;
  const int sw = lr & 7;
  const int c0 = ((( 0+lk) ^ sw) << 3);
  const int c1 = ((( 4+lk) ^ sw) << 3);
  const int c2 = ((( 8+lk) ^ sw) << 3);
  const int c3 = (((12+lk) ^ sw) << 3);
  const ushort* aw  = wa_hi + (size_t)(mh*128 + w*16)*128 + lane*8;  // per-lane src
  const ushort* awl = wa_lo + (size_t)(mh*128 + w*16)*128 + lane*8;
  ushort* areg = albuf + w*2048;                                     // wave-uniform dst

  float4v acc = {0.f,0.f,0.f,0.f};

  if (!flag){
    // -------- bf16 path: glds-streamed A, barrier-free p-loop --------
    #pragma unroll
    for (int k = 0; k < 4; ++k)
      glds16(aw + k*512, areg + k*512);
    #pragma unroll
    for (int p = 0; p < 9; ++p){
      asm volatile("s_waitcnt vmcnt(0)" ::: "memory");
      __builtin_amdgcn_sched_barrier(0);
      short8v A0 = ldfrag(areg + lr*128 + c0);
      short8v A1 = ldfrag(areg + lr*128 + c1);
      short8v A2 = ldfrag(areg + lr*128 + c2);
      short8v A3 = ldfrag(areg + lr*128 + c3);
      int pinl = (p/3)*18 + lr + (p%3);
      const ushort* bl = &bsm[pinl*264 + lk*8];
      short8v BX0 = ldfrag(bl),     BX1 = ldfrag(bl+32);
      short8v BH0 = ldfrag(bl+64),  BH1 = ldfrag(bl+96);
      short8v BL0 = ldfrag(bl+128), BL1 = ldfrag(bl+160);
      acc = __builtin_amdgcn_mfma_f32_16x16x32_bf16(A0, BX0, acc, 0,0,0);
      acc = __builtin_amdgcn_mfma_f32_16x16x32_bf16(A1, BX1, acc, 0,0,0);
      acc = __builtin_amdgcn_mfma_f32_16x16x32_bf16(A2, BH0, acc, 0,0,0);
      acc = __builtin_amdgcn_mfma_f32_16x16x32_bf16(A3, BH1, acc, 0,0,0);
      acc = __builtin_amdgcn_mfma_f32_16x16x32_bf16(A2, BL0, acc, 0,0,0);
      acc = __builtin_amdgcn_mfma_f32_16x16x32_bf16(A3, BL1, acc, 0,0,0);
      if (p < 8){
        __builtin_amdgcn_sched_barrier(0);   // pin: reads/MFMAs stay above DMA
        #pragma unroll
        for (int k = 0; k < 4; ++k)
          glds16(aw + (size_t)(p+1)*32768 + k*512, areg + k*512);
      }
    }
  } else {
    // -------- f32 path (cold): per-wave reg staging, hi then lo --------
    #pragma unroll 1
    for (int p = 0; p < 9; ++p){
      int pinl = (p/3)*18 + lr + (p%3);
      const ushort* bl = &bsm[pinl*264 + lk*8];
      short8v BX0 = ldfrag(bl),      BX1 = ldfrag(bl+32);
      short8v BH0 = ldfrag(bl+64),   BH1 = ldfrag(bl+96);
      short8v BL0 = ldfrag(bl+128),  BL1 = ldfrag(bl+160);
      short8v BXl0 = ldfrag(bl+192), BXl1 = ldfrag(bl+224);
      uint4 s0,s1,s2,s3;
      stage_ld(aw + (size_t)p*32768, s0,s1,s2,s3);
      stage_wr(areg + lane*8, s0,s1,s2,s3);
      short8v A0 = ldfrag(areg + lr*128 + c0);
      short8v A1 = ldfrag(areg + lr*128 + c1);
      short8v A2 = ldfrag(areg + lr*128 + c2);
      short8v A3 = ldfrag(areg + lr*128 + c3);
      acc = __builtin_amdgcn_mfma_f32_16x16x32_bf16(A0, BX0, acc, 0,0,0);
      acc = __builtin_amdgcn_mfma_f32_16x16x32_bf16(A1, BX1, acc, 0,0,0);
      acc = __builtin_amdgcn_mfma_f32_16x16x32_bf16(A2, BH0, acc, 0,0,0);
      acc = __builtin_amdgcn_mfma_f32_16x16x32_bf16(A3, BH1, acc, 0,0,0);
      acc = __builtin_amdgcn_mfma_f32_16x16x32_bf16(A2, BL0, acc, 0,0,0);
      acc = __builtin_amdgcn_mfma_f32_16x16x32_bf16(A3, BL1, acc, 0,0,0);
      acc = __builtin_amdgcn_mfma_f32_16x16x32_bf16(A0, BXl0, acc, 0,0,0);
      acc = __builtin_amdgcn_mfma_f32_16x16x32_bf16(A1, BXl1, acc, 0,0,0);
      stage_ld(awl + (size_t)p*32768, s0,s1,s2,s3);
      stage_wr(areg + lane*8, s0,s1,s2,s3);
      short8v Al0 = ldfrag(areg + lr*128 + c0);
      short8v Al1 = ldfrag(areg + lr*128 + c1);
      short8v Al2 = ldfrag(areg + lr*128 + c2);
      short8v Al3 = ldfrag(areg + lr*128 + c3);
      acc = __builtin_amdgcn_mfma_f32_16x16x32_bf16(Al0, BX0, acc, 0,0,0);
      acc = __builtin_amdgcn_mfma_f32_16x16x32_bf16(Al1, BX1, acc, 0,0,0);
      acc = __builtin_amdgcn_mfma_f32_16x16x32_bf16(Al2, BH0, acc, 0,0,0);
      acc = __builtin_amdgcn_mfma_f32_16x16x32_bf16(Al3, BH1, acc, 0,0,0);
    }
  }

  // epilogue: cc = mh*32 + w*4 + lk, gate = acc reg (R10-verified mapping)
  {
    int cc = mh*32 + w*4 + lk;
    int wi = cc*1024 + px;
    size_t sidx = ((size_t)(b*64 + cc))*1024 + px;
    float cprev = cst[sidx];
    float ic = acc[0] + smalls[O_CB + cc];
    float fc = acc[1] + smalls[O_CB + 64 + cc];
    float gc = acc[2] + smalls[O_CB + 128 + cc];
    float oc = acc[3] + smalls[O_CB + 192 + cc];
    float ig = sigm(ic + smalls[O_WCI + wi]*cprev);
    float fg = sigm(fc + smalls[O_WCF + wi]*cprev);
    float cnew = fg*cprev + ig*tanhc(gc);
    float og = sigm(oc + smalls[O_WCO + wi]*cnew);
    cst[sidx]  = cnew;
    hnew[sidx] = og*tanhc(cnew);
  }
}

// ---------------------------------------------------------------------------
// 1x1 projections -> bf16 MFMA-ready buffers.
// grid (128 ntiles of 8, 4 b) = 512 blocks (2/CU), block 256
// ---------------------------------------------------------------------------
__global__ __launch_bounds__(256) void k_proj(
  const float* __restrict__ hnew, const float* __restrict__ mst,
  const float* __restrict__ smalls,
  ushort* __restrict__ qb16, ushort* __restrict__ khb16, ushort* __restrict__ kmb16,
  ushort* __restrict__ vth16, ushort* __restrict__ vtm16)
{
  __shared__ float hs[64*9];
  __shared__ float ms[64*9];
  int b = blockIdx.y, n0 = blockIdx.x*8;
  int tid = threadIdx.x, nl = tid&7, rg = tid>>3;
  for (int idx = tid; idx < 512; idx += 256){
    int nn = idx & 7, ch = idx >> 3;
    hs[ch*9+nn] = hnew[((size_t)b*64+ch)*1024 + n0 + nn];
    ms[ch*9+nn] = mst [((size_t)b*64+ch)*1024 + n0 + nn];
  }
  __syncthreads();
  int n = n0 + nl;
  for (int j = 0; j < 6; ++j){
    int r = rg + 32*j;
    if (r >= 176) break;
    const float* src; const float* wrow; float bias;
    int mode, rr;
    if (r < 16)      { mode=0; rr=r;     src = hs; wrow = smalls+O_QW  + rr*64; bias = smalls[O_QB+rr]; }
    else if (r < 32) { mode=1; rr=r-16;  src = hs; wrow = smalls+O_KW  + rr*64; bias = smalls[O_KB+rr]; }
    else if (r < 48) { mode=2; rr=r-32;  src = ms; wrow = smalls+O_K2W + rr*64; bias = smalls[O_K2B+rr]; }
    else if (r < 112){ mode=3; rr=r-48;  src = hs; wrow = smalls+O_VW  + rr*64; bias = smalls[O_VB+rr]; }
    else             { mode=4; rr=r-112; src = ms; wrow = smalls+O_V2W + rr*64; bias = smalls[O_V2B+rr]; }
    float acc = bias;
    #pragma unroll
    for (int c4 = 0; c4 < 16; ++c4){
      float4 w4 = *reinterpret_cast<const float4*>(wrow + c4*4);
      acc += w4.x*src[(c4*4+0)*9+nl] + w4.y*src[(c4*4+1)*9+nl]
           + w4.z*src[(c4*4+2)*9+nl] + w4.w*src[(c4*4+3)*9+nl];
    }
    ushort v = f2bu(acc);
    if (mode <= 2){
      ushort* base = (mode==0) ? qb16 : (mode==1) ? khb16 : kmb16;
      size_t o = ((size_t)b*1024 + n)*32;
      base[o + rr] = v;
      base[o + 16 + rr] = 0;
    } else {
      ushort* base = (mode==3) ? vth16 : vtm16;
      base[((size_t)b*64 + rr)*1024 + n] = v;
    }
  }
}

// ---------------------------------------------------------------------------
// MFMA flash attention. grid (64 ntiles of 16, 4 b, 2 br) = 512 blocks (2/CU),
// block 256 = 4 waves.
// ---------------------------------------------------------------------------
__global__ __launch_bounds__(256) void k_fatt(
  const ushort* __restrict__ qb16, const ushort* __restrict__ khb16,
  const ushort* __restrict__ kmb16, const ushort* __restrict__ vth16,
  const ushort* __restrict__ vtm16, float* __restrict__ zcat)
{
  __shared__ ushort es[16*272];
  __shared__ float rs_s[4][16];
  int n0 = blockIdx.x*16, b = blockIdx.y, br = blockIdx.z;
  const ushort* kb = (br ? kmb16 : khb16) + (size_t)b*32768;
  const ushort* vt = (br ? vtm16 : vth16) + (size_t)b*65536;
  const ushort* qp = qb16 + (size_t)b*32768;
  int tid = threadIdx.x;
  int w = tid >> 6, lane = tid & 63, lr = lane & 15, lk = lane >> 4;
  const float4v Z4 = {0.f,0.f,0.f,0.f};

  short8v qf = ldfrag(qp + (size_t)(n0 + lr)*32 + lk*8);

  float4v acc[2];
  acc[0]=Z4; acc[1]=Z4;
  float rsum = 0.f;

  #pragma unroll 1
  for (int mc = 0; mc < 4; ++mc){
    int mbase = mc*256 + w*64;
    #pragma unroll
    for (int tau = 0; tau < 4; ++tau){
      short8v af = ldfrag(kb + (size_t)(mbase + tau*16 + lr)*32 + lk*8);
      float4v d = __builtin_amdgcn_mfma_f32_16x16x32_bf16(af, qf, Z4, 0,0,0);
      ushort u0 = f2bu(__expf(fminf(d[0], 60.f)));
      ushort u1 = f2bu(__expf(fminf(d[1], 60.f)));
      ushort u2 = f2bu(__expf(fminf(d[2], 60.f)));
      ushort u3 = f2bu(__expf(fminf(d[3], 60.f)));
      rsum += (bu2f(u0) + bu2f(u1)) + (bu2f(u2) + bu2f(u3));
      unsigned lo = (unsigned)u0 | ((unsigned)u1 << 16);
      unsigned hi = (unsigned)u2 | ((unsigned)u3 << 16);
      *reinterpret_cast<uint2*>(&es[lr*272 + w*64 + tau*16 + lk*4]) = make_uint2(lo, hi);
    }
    __syncthreads();
    #pragma unroll
    for (int ks = 0; ks < 8; ++ks){
      short8v av = ldfrag(vt + (size_t)(w*16 + lr)*1024 + mc*256 + ks*32 + lk*8);
      short8v bv = ldfrag(&es[lr*272 + ks*32 + lk*8]);
      acc[ks & 1] = __builtin_amdgcn_mfma_f32_16x16x32_bf16(av, bv, acc[ks & 1], 0,0,0);
    }
    __syncthreads();
  }

  {
    float r = rsum;
    r += __shfl_xor(r, 16);
    r += __shfl_xor(r, 32);
    if (lane < 16) rs_s[w][lr] = r;
  }
  __syncthreads();
  {
    float rinv = 1.0f / (rs_s[0][lr] + rs_s[1][lr] + rs_s[2][lr] + rs_s[3][lr]);
    #pragma unroll
    for (int r = 0; r < 4; ++r){
      int c = w*16 + lk*4 + r;
      zcat[((size_t)(b*128 + br*64 + c))*1024 + n0 + lr] = (acc[0][r] + acc[1][r])*rinv;
    }
  }
}

// ---------------------------------------------------------------------------
// zcomb: zt = zwT^T@zcat+z_b; comb = mw4@[zt;hnew]+m_b; gate; h_out
// writes m state, hT_hi/lo bf16, and d_out
// ---------------------------------------------------------------------------
__global__ __launch_bounds__(256) void k_zcomb(
  const float* __restrict__ zcat, const float* __restrict__ hnew,
  const float* __restrict__ smalls, const float* __restrict__ zwT,
  const float* __restrict__ mw4, const int* __restrict__ flagp,
  float* __restrict__ mst, ushort* __restrict__ hth, ushort* __restrict__ htl,
  void* __restrict__ outraw, int t)
{
  __shared__ float zin[128*9];
  __shared__ float hl [64*9];
  __shared__ float ml [64*9];
  __shared__ float zt_s[8*132];
  __shared__ float ho_s[64*9];
  __shared__ float mn_s[64*9];
  int n0 = blockIdx.x*8, b = blockIdx.y;
  int tid = threadIdx.x;
  int px = tid >> 5, lr = tid & 31;
  int flag = *flagp;
  for (int idx = tid; idx < 1024; idx += 256){
    int ch = idx >> 3, pp = idx & 7;
    zin[ch*9+pp] = zcat[((size_t)b*128 + ch)*1024 + n0 + pp];
  }
  for (int idx = tid; idx < 512; idx += 256){
    int ch = idx >> 3, pp = idx & 7;
    hl[ch*9+pp] = hnew[((size_t)b*64 + ch)*1024 + n0 + pp];
    ml[ch*9+pp] = mst [((size_t)b*64 + ch)*1024 + n0 + pp];
  }
  __syncthreads();
  {
    float4 a4 = *reinterpret_cast<const float4*>(&smalls[O_ZB + lr*4]);
    float acc0=a4.x, acc1=a4.y, acc2=a4.z, acc3=a4.w;
    #pragma unroll 4
    for (int k = 0; k < 128; ++k){
      float zv = zin[k*9 + px];
      float4 w4 = *reinterpret_cast<const float4*>(&zwT[k*128 + lr*4]);
      acc0 += w4.x*zv; acc1 += w4.y*zv; acc2 += w4.z*zv; acc3 += w4.w*zv;
    }
    *reinterpret_cast<float4*>(&zt_s[px*132 + lr*4]) = make_float4(acc0,acc1,acc2,acc3);
  }
  __syncthreads();
  {
    float acc6[6];
    #pragma unroll
    for (int i=0;i<6;++i) acc6[i] = smalls[O_MB + lr + 32*i];
    #pragma unroll 2
    for (int k4 = 0; k4 < 32; ++k4){
      float4 xv = *reinterpret_cast<const float4*>(&zt_s[px*132 + k4*4]);
      const float* wb = mw4 + (size_t)(k4*192)*4;
      #pragma unroll
      for (int i=0;i<6;++i){
        float4 w = *reinterpret_cast<const float4*>(&wb[(lr + 32*i)*4]);
        acc6[i] += w.x*xv.x + w.y*xv.y + w.z*xv.z + w.w*xv.w;
      }
    }
    #pragma unroll 2
    for (int k4 = 32; k4 < 48; ++k4){
      int ch = (k4-32)*4;
      float4 xv = make_float4(hl[ch*9+px], hl[(ch+1)*9+px], hl[(ch+2)*9+px], hl[(ch+3)*9+px]);
      const float* wb = mw4 + (size_t)(k4*192)*4;
      #pragma unroll
      for (int i=0;i<6;++i){
        float4 w = *reinterpret_cast<const float4*>(&wb[(lr + 32*i)*4]);
        acc6[i] += w.x*xv.x + w.y*xv.y + w.z*xv.z + w.w*xv.w;
      }
    }
    #pragma unroll
    for (int j=0;j<2;++j){
      int ch = lr + 32*j;
      float mold = ml[ch*9 + px];
      float gi = sigm(acc6[4+j]);
      float mnew = (1.0f-gi)*mold + gi*tanhc(acc6[2+j]);
      float ho = sigm(acc6[j])*mnew;
      ho_s[ch*9+px] = ho;
      mn_s[ch*9+px] = mnew;
    }
  }
  __syncthreads();
  for (int idx = tid; idx < 512; idx += 256){
    int ch = idx >> 3, pp = idx & 7;
    int n = n0 + pp;
    size_t gidx = ((size_t)b*64 + ch)*1024 + n;
    mst[gidx] = mn_s[ch*9+pp];
    float ho = ho_s[ch*9+pp];
    size_t tix = ((size_t)b*1024 + n)*64 + ch;
    ushort hb_ = f2bu(ho);
    hth[tix] = hb_;
    htl[tix] = f2bu(ho - bu2f(hb_));
    size_t oidx = ((size_t)(b*64+ch)*8 + t)*1024 + n;
    if (flag) ((float*)outraw)[oidx] = ho;
    else      ((bf16*)outraw)[oidx] = __float2bfloat16(ho);
  }
}

extern "C" void kernel_launch(void* const* d_in, const int* in_sizes, int n_in,
                              void* d_out, int out_size, void* d_ws, size_t ws_size,
                              hipStream_t stream)
{
  float* ws = (float*)d_ws;
  int* flag = (int*)(ws + WS_FLAG);
  float* c    = ws + WS_C;
  float* m    = ws + WS_M;
  float* hnew = ws + WS_HNEW;
  float* zcat = ws + WS_ZCAT;
  float* zwT  = ws + WS_ZWT;
  float* mw4  = ws + WS_MW4;
  ushort* qb16  = (ushort*)(ws + WS_QB16);
  ushort* khb16 = (ushort*)(ws + WS_KHB16);
  ushort* kmb16 = (ushort*)(ws + WS_KMB16);
  ushort* vth16 = (ushort*)(ws + WS_VTH16);
  ushort* vtm16 = (ushort*)(ws + WS_VTM16);
  ushort* wa_hi = (ushort*)(ws + WS_WAHI);
  ushort* wa_lo = (ushort*)(ws + WS_WALO);
  ushort* xt_hi = (ushort*)(ws + WS_XTHI);
  ushort* xt_lo = (ushort*)(ws + WS_XTLO);
  ushort* ht_hi = (ushort*)(ws + WS_HTHI);
  ushort* ht_lo = (ushort*)(ws + WS_HTLO);

  k_probe<<<1, 256, 0, stream>>>((const unsigned int*)d_in[0], flag);
  P18 pk;
  for (int i = 0; i < 18; ++i) pk.p[i] = d_in[2 + i];
  k_wconv<<<dim3(64,18), 256, 0, stream>>>(pk, flag, ws);
  k_init<<<3072, 256, 0, stream>>>(d_in[1], flag, ws);
  k_xt<<<dim3(16,32), 256, 0, stream>>>(d_in[0], flag, ws);
  k_wtrans<<<144, 256, 0, stream>>>(ws);

  for (int t = 0; t < 8; ++t){
    k_conv_mfma<<<dim3(64,2,4), 512, 0, stream>>>(flag, wa_hi, wa_lo, xt_hi, xt_lo,
                                                  ht_hi, ht_lo, ws, c, hnew, t);
    k_proj<<<dim3(128,4), 256, 0, stream>>>(hnew, m, ws, qb16, khb16, kmb16, vth16, vtm16);
    k_fatt<<<dim3(64,4,2), 256, 0, stream>>>(qb16, khb16, kmb16, vth16, vtm16, zcat);
    k_zcomb<<<dim3(128,4), 256, 0, stream>>>(zcat, hnew, ws, zwT, mw4, flag,
                                             m, ht_hi, ht_lo, d_out, t);
  }
  (void)in_sizes; (void)n_in; (void)out_size; (void)ws_size;
}

// Round 13
// 646.725 us; speedup vs baseline: 1.3584x; 1.0957x over previous
//
#include <hip/hip_runtime.h>
#include <hip/hip_bf16.h>

typedef __hip_bfloat16 bf16;
typedef unsigned short ushort;
typedef __attribute__((ext_vector_type(8))) short short8v;   // 8 bf16 = 4 VGPR
typedef __attribute__((ext_vector_type(4))) float float4v;

__device__ __forceinline__ float b2f(bf16 v){ return __bfloat162float(v); }
__device__ __forceinline__ float sigm(float x){ return 1.0f/(1.0f+__expf(-x)); }
__device__ __forceinline__ float tanhc(float x){
  x = fminf(15.0f, fmaxf(-15.0f, x));
  float e = __expf(2.0f*x);
  return (e-1.0f)/(e+1.0f);
}
__device__ __forceinline__ ushort f2bu(float f){
  bf16 h = __float2bfloat16(f); return *reinterpret_cast<ushort*>(&h);
}
__device__ __forceinline__ float bu2f(ushort u){
  return __uint_as_float(((unsigned)u)<<16);
}
__device__ __forceinline__ short8v ldfrag(const ushort* p){
  return *reinterpret_cast<const short8v*>(p);
}
// direct global->LDS DMA, 16B per lane; lds dst = uniform base + lane*16
__device__ __forceinline__ void glds16(const ushort* g, ushort* l){
  __builtin_amdgcn_global_load_lds(
    (const __attribute__((address_space(1))) unsigned int*)g,
    (__attribute__((address_space(3))) unsigned int*)l, 16, 0, 0);
}
__device__ __forceinline__ void stage_ld(const ushort* s, uint4& a0, uint4& a1,
                                         uint4& a2, uint4& a3){
  a0 = *reinterpret_cast<const uint4*>(s);
  a1 = *reinterpret_cast<const uint4*>(s+512);
  a2 = *reinterpret_cast<const uint4*>(s+1024);
  a3 = *reinterpret_cast<const uint4*>(s+1536);
}
__device__ __forceinline__ void stage_wr(ushort* d, uint4 a0, uint4 a1,
                                         uint4 a2, uint4 a3){
  *reinterpret_cast<uint4*>(d)      = a0;
  *reinterpret_cast<uint4*>(d+512)  = a1;
  *reinterpret_cast<uint4*>(d+1024) = a2;
  *reinterpret_cast<uint4*>(d+1536) = a3;
}

// ---------------------------------------------------------------------------
// ws layout (float offsets) — unchanged from R11 (zcat slot now unused)
// ---------------------------------------------------------------------------
#define WS_SMALL   0
#define WS_FLAG    262144
#define WS_ZROW    262160
#define WS_H       262208
#define WS_C       524352
#define WS_M       786496
#define WS_HNEW    1048640
#define WS_QB16    1310784
#define WS_KHB16   1376320
#define WS_KMB16   1441856
#define WS_VTH16   1507392
#define WS_VTM16   1638464
#define WS_ZCAT    1769536
#define WS_ZWT     2293824
#define WS_MW4     2310208
#define WS_WAHI    2347072
#define WS_WALO    2494528
#define WS_XTHI    2641984
#define WS_XTLO    3690560
#define WS_HTHI    4739136
#define WS_HTLO    4870208
// small-weight offsets inside WS_SMALL
#define O_CB    0
#define O_WCI   256
#define O_WCF   65792
#define O_WCO   131328
#define O_QW    196864
#define O_QB    197888
#define O_KW    197904
#define O_KB    198928
#define O_K2W   198944
#define O_K2B   199968
#define O_VW    199984
#define O_VB    204080
#define O_V2W   204144
#define O_V2B   208240
#define O_ZW    208304
#define O_ZB    224688
#define O_MW    224816
#define O_MB    261680

// ---------------------------------------------------------------------------
// dtype probe (f32 vs bf16 input data)
// ---------------------------------------------------------------------------
__global__ void k_probe(const unsigned int* __restrict__ Xu, int* __restrict__ flag){
  __shared__ int cnt;
  if (threadIdx.x == 0) cnt = 0;
  __syncthreads();
  unsigned int u = Xu[threadIdx.x];
  float f = __uint_as_float((u & 0xffffu) << 16);
  int bad = (fabsf(f) <= 1e4f) ? 0 : 1;
  atomicAdd(&cnt, bad);
  __syncthreads();
  if (threadIdx.x == 0) *flag = (cnt > 16) ? 1 : 0;
}

// ---------------------------------------------------------------------------
// convert the 18 small inputs into f32 copies in ws
// ---------------------------------------------------------------------------
struct P18 { const void* p[18]; };

__global__ __launch_bounds__(256) void k_wconv(P18 pk, const int* __restrict__ flagp,
                                               float* __restrict__ dst){
  const int ns[18]   = {256,65536,65536,65536,1024,16,1024,16,1024,16,
                        4096,64,4096,64,16384,128,36864,192};
  const int offs[18] = {O_CB,O_WCI,O_WCF,O_WCO,O_QW,O_QB,O_KW,O_KB,O_K2W,O_K2B,
                        O_VW,O_VB,O_V2W,O_V2B,O_ZW,O_ZB,O_MW,O_MB};
  int y = blockIdx.y;
  int n = ns[y];
  int flag = *flagp;
  const void* src = pk.p[y];
  for (int i = blockIdx.x*256 + threadIdx.x; i < n; i += gridDim.x*256){
    float v = flag ? ((const float*)src)[i] : b2f(((const bf16*)src)[i]);
    dst[offs[y] + i] = v;
  }
}

// transpose z_w into [k][r]; pack m_w into mw4[(k4*192 + r)*4 + q]
__global__ __launch_bounds__(256) void k_wtrans(float* __restrict__ ws){
  int i = blockIdx.x*256 + threadIdx.x;
  if (i < 16384){
    int k = i >> 7, r = i & 127;
    ws[WS_ZWT + k*128 + r] = ws[O_ZW + r*128 + k];
  }
  if (i < 36864){
    int q = i & 3; int rest = i >> 2; int r = rest % 192; int k4 = rest / 192;
    ws[WS_MW4 + i] = ws[O_MW + r*192 + k4*4 + q];
  }
}

// ---------------------------------------------------------------------------
// init: zero h,c,m + hT + zrow; build MFMA weight layout wA (hi/lo),
// CHUNK-SWIZZLED: 16B-chunk c of row m stored at chunk (c ^ (m&7)).
// ---------------------------------------------------------------------------
__global__ __launch_bounds__(256) void k_init(const void* __restrict__ conv_w,
                                              const int* __restrict__ flagp,
                                              float* __restrict__ ws){
  int i = blockIdx.x*256 + threadIdx.x;
  int flag = *flagp;
  if (i < 786432) ws[WS_H + i] = 0.0f;
  if (i < 32) ws[WS_ZROW + i] = 0.0f;
  if (i < 294912){
    int ci = i & 127;
    int j = i >> 7;           // j = p*256 + mm
    int mm = j & 255, p = j >> 8;
    int cc = mm >> 2, g = mm & 3;
    int si = ((g*64 + cc)*128 + ci)*9 + p;
    int cis = ((((ci >> 3) ^ (mm & 7)) << 3) | (ci & 7));
    int di = (j << 7) + cis;
    ushort* wah = (ushort*)(ws + WS_WAHI);
    ushort* wal = (ushort*)(ws + WS_WALO);
    if (flag){
      float f = ((const float*)conv_w)[si];
      ushort hi = f2bu(f);
      wah[di] = hi;
      wal[di] = f2bu(f - bu2f(hi));
    } else {
      wah[di] = ((const ushort*)conv_w)[si];
    }
  }
  if (i < 131072){
    ((unsigned*)(ws + WS_HTHI))[i] = 0u;
    ((unsigned*)(ws + WS_HTLO))[i] = 0u;
  }
}

// ---------------------------------------------------------------------------
// X transpose: XT[b][t][px][ci]
// ---------------------------------------------------------------------------
__global__ __launch_bounds__(256) void k_xt(const void* __restrict__ Xraw,
                                            const int* __restrict__ flagp,
                                            float* __restrict__ ws){
  __shared__ ushort hi_s[64][66];
  __shared__ ushort lo_s[64][66];
  int pt = blockIdx.x, s = blockIdx.y;
  int b = s >> 3, t = s & 7;
  int flag = *flagp;
  int tid = threadIdx.x;
  for (int k = 0; k < 16; ++k){
    int idx = tid + k*256;
    int ci = idx >> 6, pxl = idx & 63;
    size_t si = ((size_t)(b*64 + ci)*8 + t)*1024 + pt*64 + pxl;
    if (flag){
      float f = ((const float*)Xraw)[si];
      ushort h = f2bu(f);
      hi_s[pxl][ci] = h;
      lo_s[pxl][ci] = f2bu(f - bu2f(h));
    } else {
      hi_s[pxl][ci] = ((const ushort*)Xraw)[si];
    }
  }
  __syncthreads();
  ushort* xh = (ushort*)(ws + WS_XTHI) + ((size_t)s*1024 + pt*64)*64;
  ushort* xl = (ushort*)(ws + WS_XTLO) + ((size_t)s*1024 + pt*64)*64;
  for (int k = 0; k < 16; ++k){
    int idx = tid + k*256;
    int pxl = idx >> 6, ci = idx & 63;
    xh[pxl*64 + ci] = hi_s[pxl][ci];
    if (flag) xl[pxl*64 + ci] = lo_s[pxl][ci];
  }
}

// ---------------------------------------------------------------------------
// conv 3x3 + peephole LSTM via MFMA implicit GEMM — unchanged from R11.
// ---------------------------------------------------------------------------
__global__ __launch_bounds__(512, 4) void k_conv_mfma(
  const int* __restrict__ flagp,
  const ushort* __restrict__ wa_hi, const ushort* __restrict__ wa_lo,
  const ushort* __restrict__ xt_hi, const ushort* __restrict__ xt_lo,
  const ushort* __restrict__ ht_hi, const ushort* __restrict__ ht_lo,
  const float* __restrict__ smalls, float* __restrict__ cst,
  float* __restrict__ hnew, int t)
{
  __shared__ ushort albuf[16384];    // 32 KB: 8 wave-private 4KB A slices
  __shared__ ushort bsm[54*264];     // 27.8 KB: B halo (all 9 taps)
  int nt = blockIdx.x, mh = blockIdx.y, b = blockIdx.z;
  int tid = threadIdx.x;
  int flag = *flagp;
  int ytile = nt >> 1, x0 = (nt & 1) * 16;

  const ushort* xb  = xt_hi + ((size_t)(b*8 + t))*65536;
  const ushort* xlb = xt_lo + ((size_t)(b*8 + t))*65536;
  const ushort* hb  = ht_hi + (size_t)b*65536;
  const ushort* hlb = ht_lo + (size_t)b*65536;

  const uint4 Z16 = make_uint4(0,0,0,0);
  for (int idx = tid; idx < 1728; idx += 512){
    int slot = idx >> 5, c = idx & 31;
    int rr = slot / 18, xi = slot - rr*18;
    int gy = ytile - 1 + rr, gx = x0 - 1 + xi;
    bool valid = (gy >= 0) & (gy < 32) & (gx >= 0) & (gx < 32);
    int px = gy*32 + gx;
    uint4 v = Z16;
    if (valid){
      if (c < 8)       v = *reinterpret_cast<const uint4*>(xb  + (size_t)px*64 + c*8);
      else if (c < 16) v = *reinterpret_cast<const uint4*>(hb  + (size_t)px*64 + (c-8)*8);
      else if (c < 24) v = *reinterpret_cast<const uint4*>(hlb + (size_t)px*64 + (c-16)*8);
      else if (flag)   v = *reinterpret_cast<const uint4*>(xlb + (size_t)px*64 + (c-24)*8);
    }
    *reinterpret_cast<uint4*>(&bsm[slot*264 + c*8]) = v;
  }
  __syncthreads();

  int w = tid >> 6, lane = tid & 63, lr = lane & 15, lk = lane >> 4;
  int px = nt*16 + lr;
  const int sw = lr & 7;
  const int c0 = ((( 0+lk) ^ sw) << 3);
  const int c1 = ((( 4+lk) ^ sw) << 3);
  const int c2 = ((( 8+lk) ^ sw) << 3);
  const int c3 = (((12+lk) ^ sw) << 3);
  const ushort* aw  = wa_hi + (size_t)(mh*128 + w*16)*128 + lane*8;
  const ushort* awl = wa_lo + (size_t)(mh*128 + w*16)*128 + lane*8;
  ushort* areg = albuf + w*2048;

  float4v acc = {0.f,0.f,0.f,0.f};

  if (!flag){
    #pragma unroll
    for (int k = 0; k < 4; ++k)
      glds16(aw + k*512, areg + k*512);
    #pragma unroll
    for (int p = 0; p < 9; ++p){
      asm volatile("s_waitcnt vmcnt(0)" ::: "memory");
      __builtin_amdgcn_sched_barrier(0);
      short8v A0 = ldfrag(areg + lr*128 + c0);
      short8v A1 = ldfrag(areg + lr*128 + c1);
      short8v A2 = ldfrag(areg + lr*128 + c2);
      short8v A3 = ldfrag(areg + lr*128 + c3);
      int pinl = (p/3)*18 + lr + (p%3);
      const ushort* bl = &bsm[pinl*264 + lk*8];
      short8v BX0 = ldfrag(bl),     BX1 = ldfrag(bl+32);
      short8v BH0 = ldfrag(bl+64),  BH1 = ldfrag(bl+96);
      short8v BL0 = ldfrag(bl+128), BL1 = ldfrag(bl+160);
      acc = __builtin_amdgcn_mfma_f32_16x16x32_bf16(A0, BX0, acc, 0,0,0);
      acc = __builtin_amdgcn_mfma_f32_16x16x32_bf16(A1, BX1, acc, 0,0,0);
      acc = __builtin_amdgcn_mfma_f32_16x16x32_bf16(A2, BH0, acc, 0,0,0);
      acc = __builtin_amdgcn_mfma_f32_16x16x32_bf16(A3, BH1, acc, 0,0,0);
      acc = __builtin_amdgcn_mfma_f32_16x16x32_bf16(A2, BL0, acc, 0,0,0);
      acc = __builtin_amdgcn_mfma_f32_16x16x32_bf16(A3, BL1, acc, 0,0,0);
      if (p < 8){
        __builtin_amdgcn_sched_barrier(0);
        #pragma unroll
        for (int k = 0; k < 4; ++k)
          glds16(aw + (size_t)(p+1)*32768 + k*512, areg + k*512);
      }
    }
  } else {
    #pragma unroll 1
    for (int p = 0; p < 9; ++p){
      int pinl = (p/3)*18 + lr + (p%3);
      const ushort* bl = &bsm[pinl*264 + lk*8];
      short8v BX0 = ldfrag(bl),      BX1 = ldfrag(bl+32);
      short8v BH0 = ldfrag(bl+64),   BH1 = ldfrag(bl+96);
      short8v BL0 = ldfrag(bl+128),  BL1 = ldfrag(bl+160);
      short8v BXl0 = ldfrag(bl+192), BXl1 = ldfrag(bl+224);
      uint4 s0,s1,s2,s3;
      stage_ld(aw + (size_t)p*32768, s0,s1,s2,s3);
      stage_wr(areg + lane*8, s0,s1,s2,s3);
      short8v A0 = ldfrag(areg + lr*128 + c0);
      short8v A1 = ldfrag(areg + lr*128 + c1);
      short8v A2 = ldfrag(areg + lr*128 + c2);
      short8v A3 = ldfrag(areg + lr*128 + c3);
      acc = __builtin_amdgcn_mfma_f32_16x16x32_bf16(A0, BX0, acc, 0,0,0);
      acc = __builtin_amdgcn_mfma_f32_16x16x32_bf16(A1, BX1, acc, 0,0,0);
      acc = __builtin_amdgcn_mfma_f32_16x16x32_bf16(A2, BH0, acc, 0,0,0);
      acc = __builtin_amdgcn_mfma_f32_16x16x32_bf16(A3, BH1, acc, 0,0,0);
      acc = __builtin_amdgcn_mfma_f32_16x16x32_bf16(A2, BL0, acc, 0,0,0);
      acc = __builtin_amdgcn_mfma_f32_16x16x32_bf16(A3, BL1, acc, 0,0,0);
      acc = __builtin_amdgcn_mfma_f32_16x16x32_bf16(A0, BXl0, acc, 0,0,0);
      acc = __builtin_amdgcn_mfma_f32_16x16x32_bf16(A1, BXl1, acc, 0,0,0);
      stage_ld(awl + (size_t)p*32768, s0,s1,s2,s3);
      stage_wr(areg + lane*8, s0,s1,s2,s3);
      short8v Al0 = ldfrag(areg + lr*128 + c0);
      short8v Al1 = ldfrag(areg + lr*128 + c1);
      short8v Al2 = ldfrag(areg + lr*128 + c2);
      short8v Al3 = ldfrag(areg + lr*128 + c3);
      acc = __builtin_amdgcn_mfma_f32_16x16x32_bf16(Al0, BX0, acc, 0,0,0);
      acc = __builtin_amdgcn_mfma_f32_16x16x32_bf16(Al1, BX1, acc, 0,0,0);
      acc = __builtin_amdgcn_mfma_f32_16x16x32_bf16(Al2, BH0, acc, 0,0,0);
      acc = __builtin_amdgcn_mfma_f32_16x16x32_bf16(Al3, BH1, acc, 0,0,0);
    }
  }

  {
    int cc = mh*32 + w*4 + lk;
    int wi = cc*1024 + px;
    size_t sidx = ((size_t)(b*64 + cc))*1024 + px;
    float cprev = cst[sidx];
    float ic = acc[0] + smalls[O_CB + cc];
    float fc = acc[1] + smalls[O_CB + 64 + cc];
    float gc = acc[2] + smalls[O_CB + 128 + cc];
    float oc = acc[3] + smalls[O_CB + 192 + cc];
    float ig = sigm(ic + smalls[O_WCI + wi]*cprev);
    float fg = sigm(fc + smalls[O_WCF + wi]*cprev);
    float cnew = fg*cprev + ig*tanhc(gc);
    float og = sigm(oc + smalls[O_WCO + wi]*cnew);
    cst[sidx]  = cnew;
    hnew[sidx] = og*tanhc(cnew);
  }
}

// ---------------------------------------------------------------------------
// 1x1 projections -> bf16 MFMA-ready buffers — unchanged from R11.
// ---------------------------------------------------------------------------
__global__ __launch_bounds__(256) void k_proj(
  const float* __restrict__ hnew, const float* __restrict__ mst,
  const float* __restrict__ smalls,
  ushort* __restrict__ qb16, ushort* __restrict__ khb16, ushort* __restrict__ kmb16,
  ushort* __restrict__ vth16, ushort* __restrict__ vtm16)
{
  __shared__ float hs[64*9];
  __shared__ float ms[64*9];
  int b = blockIdx.y, n0 = blockIdx.x*8;
  int tid = threadIdx.x, nl = tid&7, rg = tid>>3;
  for (int idx = tid; idx < 512; idx += 256){
    int nn = idx & 7, ch = idx >> 3;
    hs[ch*9+nn] = hnew[((size_t)b*64+ch)*1024 + n0 + nn];
    ms[ch*9+nn] = mst [((size_t)b*64+ch)*1024 + n0 + nn];
  }
  __syncthreads();
  int n = n0 + nl;
  for (int j = 0; j < 6; ++j){
    int r = rg + 32*j;
    if (r >= 176) break;
    const float* src; const float* wrow; float bias;
    int mode, rr;
    if (r < 16)      { mode=0; rr=r;     src = hs; wrow = smalls+O_QW  + rr*64; bias = smalls[O_QB+rr]; }
    else if (r < 32) { mode=1; rr=r-16;  src = hs; wrow = smalls+O_KW  + rr*64; bias = smalls[O_KB+rr]; }
    else if (r < 48) { mode=2; rr=r-32;  src = ms; wrow = smalls+O_K2W + rr*64; bias = smalls[O_K2B+rr]; }
    else if (r < 112){ mode=3; rr=r-48;  src = hs; wrow = smalls+O_VW  + rr*64; bias = smalls[O_VB+rr]; }
    else             { mode=4; rr=r-112; src = ms; wrow = smalls+O_V2W + rr*64; bias = smalls[O_V2B+rr]; }
    float acc = bias;
    #pragma unroll
    for (int c4 = 0; c4 < 16; ++c4){
      float4 w4 = *reinterpret_cast<const float4*>(wrow + c4*4);
      acc += w4.x*src[(c4*4+0)*9+nl] + w4.y*src[(c4*4+1)*9+nl]
           + w4.z*src[(c4*4+2)*9+nl] + w4.w*src[(c4*4+3)*9+nl];
    }
    ushort v = f2bu(acc);
    if (mode <= 2){
      ushort* base = (mode==0) ? qb16 : (mode==1) ? khb16 : kmb16;
      size_t o = ((size_t)b*1024 + n)*32;
      base[o + rr] = v;
      base[o + 16 + rr] = 0;
    } else {
      ushort* base = (mode==3) ? vth16 : vtm16;
      base[((size_t)b*64 + rr)*1024 + n] = v;
    }
  }
}

// ---------------------------------------------------------------------------
// FUSED MFMA flash attention (both branches) + zcomb.
// grid (64 ntiles of 16, 4 b) = 256 blocks, block 512 = 8 waves:
//   waves 0-3 -> branch 0 (kh/vh), waves 4-7 -> branch 1 (km/vm);
//   wave quarter wq handles m-slice wq*64 within each 256-m chunk.
// Attention output (normalized, f32) goes to LDS zin[128ch][17] — no zcat
// global round-trip. Then zcomb phases run in-block (16 px, 512 thr).
// ---------------------------------------------------------------------------
__global__ __launch_bounds__(512) void k_fattz(
  const ushort* __restrict__ qb16, const ushort* __restrict__ khb16,
  const ushort* __restrict__ kmb16, const ushort* __restrict__ vth16,
  const ushort* __restrict__ vtm16,
  const float* __restrict__ hnew, const float* __restrict__ smalls,
  const float* __restrict__ zwT, const float* __restrict__ mw4,
  const int* __restrict__ flagp,
  float* __restrict__ mst, ushort* __restrict__ hth, ushort* __restrict__ htl,
  void* __restrict__ outraw, int t)
{
  __shared__ ushort es[2*16*272];     // per-branch P tiles (B-frag layout)
  __shared__ float rs_s[2][4][16];
  __shared__ float zin[128*17];       // fused zcat (f32, bit-identical)
  __shared__ float zt_s[16*132];
  __shared__ float hl[64*17];
  __shared__ float ml[64*17];
  __shared__ float ho_s[64*17];
  __shared__ float mn_s[64*17];
  int nt = blockIdx.x, b = blockIdx.y;
  int n0 = nt*16;
  int tid = threadIdx.x;
  int w = tid >> 6, lane = tid & 63, lr = lane & 15, lk = lane >> 4;
  int br = w >> 2, wq = w & 3;
  int flag = *flagp;
  const float4v Z4 = {0.f,0.f,0.f,0.f};

  const ushort* kb = (br ? kmb16 : khb16) + (size_t)b*32768;
  const ushort* vt = (br ? vtm16 : vth16) + (size_t)b*65536;
  const ushort* qp = qb16 + (size_t)b*32768;
  ushort* esb = es + br*4352;

  // stage hl/ml while attention runs (independent of phase A)
  for (int idx = tid; idx < 1024; idx += 512){
    int ch = idx >> 4, pp = idx & 15;
    hl[ch*17+pp] = hnew[((size_t)b*64 + ch)*1024 + n0 + pp];
    ml[ch*17+pp] = mst [((size_t)b*64 + ch)*1024 + n0 + pp];
  }

  short8v qf = ldfrag(qp + (size_t)(n0 + lr)*32 + lk*8);

  float4v acc[2];
  acc[0]=Z4; acc[1]=Z4;
  float rsum = 0.f;

  #pragma unroll 1
  for (int mc = 0; mc < 4; ++mc){
    int mbase = mc*256 + wq*64;
    #pragma unroll
    for (int tau = 0; tau < 4; ++tau){
      short8v af = ldfrag(kb + (size_t)(mbase + tau*16 + lr)*32 + lk*8);
      float4v d = __builtin_amdgcn_mfma_f32_16x16x32_bf16(af, qf, Z4, 0,0,0);
      ushort u0 = f2bu(__expf(fminf(d[0], 60.f)));
      ushort u1 = f2bu(__expf(fminf(d[1], 60.f)));
      ushort u2 = f2bu(__expf(fminf(d[2], 60.f)));
      ushort u3 = f2bu(__expf(fminf(d[3], 60.f)));
      rsum += (bu2f(u0) + bu2f(u1)) + (bu2f(u2) + bu2f(u3));
      unsigned lo = (unsigned)u0 | ((unsigned)u1 << 16);
      unsigned hi = (unsigned)u2 | ((unsigned)u3 << 16);
      *reinterpret_cast<uint2*>(&esb[lr*272 + wq*64 + tau*16 + lk*4]) = make_uint2(lo, hi);
    }
    __syncthreads();
    #pragma unroll
    for (int ks = 0; ks < 8; ++ks){
      short8v av = ldfrag(vt + (size_t)(wq*16 + lr)*1024 + mc*256 + ks*32 + lk*8);
      short8v bv = ldfrag(&esb[lr*272 + ks*32 + lk*8]);
      acc[ks & 1] = __builtin_amdgcn_mfma_f32_16x16x32_bf16(av, bv, acc[ks & 1], 0,0,0);
    }
    __syncthreads();
  }

  {
    float r = rsum;
    r += __shfl_xor(r, 16);
    r += __shfl_xor(r, 32);
    if (lane < 16) rs_s[br][wq][lr] = r;
  }
  __syncthreads();
  {
    float rinv = 1.0f / (rs_s[br][0][lr] + rs_s[br][1][lr] + rs_s[br][2][lr] + rs_s[br][3][lr]);
    #pragma unroll
    for (int r = 0; r < 4; ++r){
      int ch = br*64 + wq*16 + lk*4 + r;
      zin[ch*17 + lr] = (acc[0][r] + acc[1][r])*rinv;
    }
  }
  __syncthreads();

  // ---------------- zcomb phase (16 px, 512 threads) ----------------
  int px = tid >> 5, lr2 = tid & 31;
  {
    float4 a4 = *reinterpret_cast<const float4*>(&smalls[O_ZB + lr2*4]);
    float acc0=a4.x, acc1=a4.y, acc2=a4.z, acc3=a4.w;
    #pragma unroll 4
    for (int k = 0; k < 128; ++k){
      float zv = zin[k*17 + px];
      float4 w4 = *reinterpret_cast<const float4*>(&zwT[k*128 + lr2*4]);
      acc0 += w4.x*zv; acc1 += w4.y*zv; acc2 += w4.z*zv; acc3 += w4.w*zv;
    }
    *reinterpret_cast<float4*>(&zt_s[px*132 + lr2*4]) = make_float4(acc0,acc1,acc2,acc3);
  }
  __syncthreads();
  {
    float acc6[6];
    #pragma unroll
    for (int i=0;i<6;++i) acc6[i] = smalls[O_MB + lr2 + 32*i];
    #pragma unroll 2
    for (int k4 = 0; k4 < 32; ++k4){
      float4 xv = *reinterpret_cast<const float4*>(&zt_s[px*132 + k4*4]);
      const float* wb = mw4 + (size_t)(k4*192)*4;
      #pragma unroll
      for (int i=0;i<6;++i){
        float4 wv = *reinterpret_cast<const float4*>(&wb[(lr2 + 32*i)*4]);
        acc6[i] += wv.x*xv.x + wv.y*xv.y + wv.z*xv.z + wv.w*xv.w;
      }
    }
    #pragma unroll 2
    for (int k4 = 32; k4 < 48; ++k4){
      int ch = (k4-32)*4;
      float4 xv = make_float4(hl[ch*17+px], hl[(ch+1)*17+px], hl[(ch+2)*17+px], hl[(ch+3)*17+px]);
      const float* wb = mw4 + (size_t)(k4*192)*4;
      #pragma unroll
      for (int i=0;i<6;++i){
        float4 wv = *reinterpret_cast<const float4*>(&wb[(lr2 + 32*i)*4]);
        acc6[i] += wv.x*xv.x + wv.y*xv.y + wv.z*xv.z + wv.w*xv.w;
      }
    }
    #pragma unroll
    for (int j=0;j<2;++j){
      int ch = lr2 + 32*j;
      float mold = ml[ch*17 + px];
      float gi = sigm(acc6[4+j]);
      float mnew = (1.0f-gi)*mold + gi*tanhc(acc6[2+j]);
      float ho = sigm(acc6[j])*mnew;
      ho_s[ch*17+px] = ho;
      mn_s[ch*17+px] = mnew;
    }
  }
  __syncthreads();
  for (int idx = tid; idx < 1024; idx += 512){
    int ch = idx >> 4, pp = idx & 15;
    int n = n0 + pp;
    size_t gidx = ((size_t)b*64 + ch)*1024 + n;
    mst[gidx] = mn_s[ch*17+pp];
    float ho = ho_s[ch*17+pp];
    size_t tix = ((size_t)b*1024 + n)*64 + ch;
    ushort hb_ = f2bu(ho);
    hth[tix] = hb_;
    htl[tix] = f2bu(ho - bu2f(hb_));
    size_t oidx = ((size_t)(b*64+ch)*8 + t)*1024 + n;
    if (flag) ((float*)outraw)[oidx] = ho;
    else      ((bf16*)outraw)[oidx] = __float2bfloat16(ho);
  }
}

extern "C" void kernel_launch(void* const* d_in, const int* in_sizes, int n_in,
                              void* d_out, int out_size, void* d_ws, size_t ws_size,
                              hipStream_t stream)
{
  float* ws = (float*)d_ws;
  int* flag = (int*)(ws + WS_FLAG);
  float* c    = ws + WS_C;
  float* m    = ws + WS_M;
  float* hnew = ws + WS_HNEW;
  float* zwT  = ws + WS_ZWT;
  float* mw4  = ws + WS_MW4;
  ushort* qb16  = (ushort*)(ws + WS_QB16);
  ushort* khb16 = (ushort*)(ws + WS_KHB16);
  ushort* kmb16 = (ushort*)(ws + WS_KMB16);
  ushort* vth16 = (ushort*)(ws + WS_VTH16);
  ushort* vtm16 = (ushort*)(ws + WS_VTM16);
  ushort* wa_hi = (ushort*)(ws + WS_WAHI);
  ushort* wa_lo = (ushort*)(ws + WS_WALO);
  ushort* xt_hi = (ushort*)(ws + WS_XTHI);
  ushort* xt_lo = (ushort*)(ws + WS_XTLO);
  ushort* ht_hi = (ushort*)(ws + WS_HTHI);
  ushort* ht_lo = (ushort*)(ws + WS_HTLO);

  k_probe<<<1, 256, 0, stream>>>((const unsigned int*)d_in[0], flag);
  P18 pk;
  for (int i = 0; i < 18; ++i) pk.p[i] = d_in[2 + i];
  k_wconv<<<dim3(64,18), 256, 0, stream>>>(pk, flag, ws);
  k_init<<<3072, 256, 0, stream>>>(d_in[1], flag, ws);
  k_xt<<<dim3(16,32), 256, 0, stream>>>(d_in[0], flag, ws);
  k_wtrans<<<144, 256, 0, stream>>>(ws);

  for (int t = 0; t < 8; ++t){
    k_conv_mfma<<<dim3(64,2,4), 512, 0, stream>>>(flag, wa_hi, wa_lo, xt_hi, xt_lo,
                                                  ht_hi, ht_lo, ws, c, hnew, t);
    k_proj<<<dim3(128,4), 256, 0, stream>>>(hnew, m, ws, qb16, khb16, kmb16, vth16, vtm16);
    k_fattz<<<dim3(64,4), 512, 0, stream>>>(qb16, khb16, kmb16, vth16, vtm16,
                                            hnew, ws, zwT, mw4, flag,
                                            m, ht_hi, ht_lo, d_out, t);
  }
  (void)in_sizes; (void)n_in; (void)out_size; (void)ws_size;
}

// Round 14
// 506.570 us; speedup vs baseline: 1.7342x; 1.2767x over previous
//
#include <hip/hip_runtime.h>
#include <hip/hip_bf16.h>

typedef __hip_bfloat16 bf16;
typedef unsigned short ushort;
typedef __attribute__((ext_vector_type(8))) short short8v;   // 8 bf16 = 4 VGPR
typedef __attribute__((ext_vector_type(4))) float float4v;

__device__ __forceinline__ float b2f(bf16 v){ return __bfloat162float(v); }
__device__ __forceinline__ float sigm(float x){ return 1.0f/(1.0f+__expf(-x)); }
__device__ __forceinline__ float tanhc(float x){
  x = fminf(15.0f, fmaxf(-15.0f, x));
  float e = __expf(2.0f*x);
  return (e-1.0f)/(e+1.0f);
}
__device__ __forceinline__ ushort f2bu(float f){
  bf16 h = __float2bfloat16(f); return *reinterpret_cast<ushort*>(&h);
}
__device__ __forceinline__ float bu2f(ushort u){
  return __uint_as_float(((unsigned)u)<<16);
}
__device__ __forceinline__ short8v ldfrag(const ushort* p){
  return *reinterpret_cast<const short8v*>(p);
}
// direct global->LDS DMA, 16B per lane; lds dst = uniform base + lane*16
__device__ __forceinline__ void glds16(const ushort* g, ushort* l){
  __builtin_amdgcn_global_load_lds(
    (const __attribute__((address_space(1))) unsigned int*)g,
    (__attribute__((address_space(3))) unsigned int*)l, 16, 0, 0);
}
__device__ __forceinline__ void stage_ld(const ushort* s, uint4& a0, uint4& a1,
                                         uint4& a2, uint4& a3){
  a0 = *reinterpret_cast<const uint4*>(s);
  a1 = *reinterpret_cast<const uint4*>(s+512);
  a2 = *reinterpret_cast<const uint4*>(s+1024);
  a3 = *reinterpret_cast<const uint4*>(s+1536);
}
__device__ __forceinline__ void stage_wr(ushort* d, uint4 a0, uint4 a1,
                                         uint4 a2, uint4 a3){
  *reinterpret_cast<uint4*>(d)      = a0;
  *reinterpret_cast<uint4*>(d+512)  = a1;
  *reinterpret_cast<uint4*>(d+1024) = a2;
  *reinterpret_cast<uint4*>(d+1536) = a3;
}

// ---------------------------------------------------------------------------
// ws layout (float offsets)
// ---------------------------------------------------------------------------
#define WS_SMALL   0
#define WS_FLAG    262144
#define WS_ZROW    262160
#define WS_H       262208
#define WS_C       524352
#define WS_M       786496
#define WS_HNEW    1048640
#define WS_QB16    1310784
#define WS_KHB16   1376320
#define WS_KMB16   1441856
#define WS_VTH16   1507392
#define WS_VTM16   1638464
#define WS_ZCAT    1769536     // dead
#define WS_ZW16H   2293824     // 8192 f  (128x128 bf16 hi)
#define WS_ZW16L   2302016     // 8192 f
#define WS_MW16H   2310208     // 18432 f (192x192 bf16 hi)
#define WS_MW16L   2328640     // 18432 f
#define WS_WAHI    2347072
#define WS_WALO    2494528
#define WS_XTHI    2641984
#define WS_XTLO    3690560
#define WS_HTHI    4739136
#define WS_HTLO    4870208
// small-weight offsets inside WS_SMALL
#define O_CB    0
#define O_WCI   256
#define O_WCF   65792
#define O_WCO   131328
#define O_QW    196864
#define O_QB    197888
#define O_KW    197904
#define O_KB    198928
#define O_K2W   198944
#define O_K2B   199968
#define O_VW    199984
#define O_VB    204080
#define O_V2W   204144
#define O_V2B   208240
#define O_ZW    208304
#define O_ZB    224688
#define O_MW    224816
#define O_MB    261680

// ---------------------------------------------------------------------------
// dtype probe (f32 vs bf16 input data)
// ---------------------------------------------------------------------------
__global__ void k_probe(const unsigned int* __restrict__ Xu, int* __restrict__ flag){
  __shared__ int cnt;
  if (threadIdx.x == 0) cnt = 0;
  __syncthreads();
  unsigned int u = Xu[threadIdx.x];
  float f = __uint_as_float((u & 0xffffu) << 16);
  int bad = (fabsf(f) <= 1e4f) ? 0 : 1;
  atomicAdd(&cnt, bad);
  __syncthreads();
  if (threadIdx.x == 0) *flag = (cnt > 16) ? 1 : 0;
}

// ---------------------------------------------------------------------------
// convert the 18 small inputs into f32 copies in ws
// ---------------------------------------------------------------------------
struct P18 { const void* p[18]; };

__global__ __launch_bounds__(256) void k_wconv(P18 pk, const int* __restrict__ flagp,
                                               float* __restrict__ dst){
  const int ns[18]   = {256,65536,65536,65536,1024,16,1024,16,1024,16,
                        4096,64,4096,64,16384,128,36864,192};
  const int offs[18] = {O_CB,O_WCI,O_WCF,O_WCO,O_QW,O_QB,O_KW,O_KB,O_K2W,O_K2B,
                        O_VW,O_VB,O_V2W,O_V2B,O_ZW,O_ZB,O_MW,O_MB};
  int y = blockIdx.y;
  int n = ns[y];
  int flag = *flagp;
  const void* src = pk.p[y];
  for (int i = blockIdx.x*256 + threadIdx.x; i < n; i += gridDim.x*256){
    float v = flag ? ((const float*)src)[i] : b2f(((const bf16*)src)[i]);
    dst[offs[y] + i] = v;
  }
}

// build row-major bf16 (hi/lo) copies of z_w (128x128) and m_w (192x192)
__global__ __launch_bounds__(256) void k_wtrans(float* __restrict__ ws){
  int i = blockIdx.x*256 + threadIdx.x;
  if (i < 16384){
    float f = ws[O_ZW + i];
    ushort h = f2bu(f);
    ((ushort*)(ws + WS_ZW16H))[i] = h;
    ((ushort*)(ws + WS_ZW16L))[i] = f2bu(f - bu2f(h));
  }
  if (i < 36864){
    float f = ws[O_MW + i];
    ushort h = f2bu(f);
    ((ushort*)(ws + WS_MW16H))[i] = h;
    ((ushort*)(ws + WS_MW16L))[i] = f2bu(f - bu2f(h));
  }
}

// ---------------------------------------------------------------------------
// init: zero h,c,m + hT + zrow; build MFMA weight layout wA (hi/lo),
// CHUNK-SWIZZLED: 16B-chunk c of row m stored at chunk (c ^ (m&7)).
// ---------------------------------------------------------------------------
__global__ __launch_bounds__(256) void k_init(const void* __restrict__ conv_w,
                                              const int* __restrict__ flagp,
                                              float* __restrict__ ws){
  int i = blockIdx.x*256 + threadIdx.x;
  int flag = *flagp;
  if (i < 786432) ws[WS_H + i] = 0.0f;
  if (i < 32) ws[WS_ZROW + i] = 0.0f;
  if (i < 294912){
    int ci = i & 127;
    int j = i >> 7;           // j = p*256 + mm
    int mm = j & 255, p = j >> 8;
    int cc = mm >> 2, g = mm & 3;
    int si = ((g*64 + cc)*128 + ci)*9 + p;
    int cis = ((((ci >> 3) ^ (mm & 7)) << 3) | (ci & 7));
    int di = (j << 7) + cis;
    ushort* wah = (ushort*)(ws + WS_WAHI);
    ushort* wal = (ushort*)(ws + WS_WALO);
    if (flag){
      float f = ((const float*)conv_w)[si];
      ushort hi = f2bu(f);
      wah[di] = hi;
      wal[di] = f2bu(f - bu2f(hi));
    } else {
      wah[di] = ((const ushort*)conv_w)[si];
    }
  }
  if (i < 131072){
    ((unsigned*)(ws + WS_HTHI))[i] = 0u;
    ((unsigned*)(ws + WS_HTLO))[i] = 0u;
  }
}

// ---------------------------------------------------------------------------
// X transpose: XT[b][t][px][ci]
// ---------------------------------------------------------------------------
__global__ __launch_bounds__(256) void k_xt(const void* __restrict__ Xraw,
                                            const int* __restrict__ flagp,
                                            float* __restrict__ ws){
  __shared__ ushort hi_s[64][66];
  __shared__ ushort lo_s[64][66];
  int pt = blockIdx.x, s = blockIdx.y;
  int b = s >> 3, t = s & 7;
  int flag = *flagp;
  int tid = threadIdx.x;
  for (int k = 0; k < 16; ++k){
    int idx = tid + k*256;
    int ci = idx >> 6, pxl = idx & 63;
    size_t si = ((size_t)(b*64 + ci)*8 + t)*1024 + pt*64 + pxl;
    if (flag){
      float f = ((const float*)Xraw)[si];
      ushort h = f2bu(f);
      hi_s[pxl][ci] = h;
      lo_s[pxl][ci] = f2bu(f - bu2f(h));
    } else {
      hi_s[pxl][ci] = ((const ushort*)Xraw)[si];
    }
  }
  __syncthreads();
  ushort* xh = (ushort*)(ws + WS_XTHI) + ((size_t)s*1024 + pt*64)*64;
  ushort* xl = (ushort*)(ws + WS_XTLO) + ((size_t)s*1024 + pt*64)*64;
  for (int k = 0; k < 16; ++k){
    int idx = tid + k*256;
    int pxl = idx >> 6, ci = idx & 63;
    xh[pxl*64 + ci] = hi_s[pxl][ci];
    if (flag) xl[pxl*64 + ci] = lo_s[pxl][ci];
  }
}

// ---------------------------------------------------------------------------
// conv 3x3 + peephole LSTM via MFMA implicit GEMM — unchanged from R11.
// ---------------------------------------------------------------------------
__global__ __launch_bounds__(512, 4) void k_conv_mfma(
  const int* __restrict__ flagp,
  const ushort* __restrict__ wa_hi, const ushort* __restrict__ wa_lo,
  const ushort* __restrict__ xt_hi, const ushort* __restrict__ xt_lo,
  const ushort* __restrict__ ht_hi, const ushort* __restrict__ ht_lo,
  const float* __restrict__ smalls, float* __restrict__ cst,
  float* __restrict__ hnew, int t)
{
  __shared__ ushort albuf[16384];
  __shared__ ushort bsm[54*264];
  int nt = blockIdx.x, mh = blockIdx.y, b = blockIdx.z;
  int tid = threadIdx.x;
  int flag = *flagp;
  int ytile = nt >> 1, x0 = (nt & 1) * 16;

  const ushort* xb  = xt_hi + ((size_t)(b*8 + t))*65536;
  const ushort* xlb = xt_lo + ((size_t)(b*8 + t))*65536;
  const ushort* hb  = ht_hi + (size_t)b*65536;
  const ushort* hlb = ht_lo + (size_t)b*65536;

  const uint4 Z16 = make_uint4(0,0,0,0);
  for (int idx = tid; idx < 1728; idx += 512){
    int slot = idx >> 5, c = idx & 31;
    int rr = slot / 18, xi = slot - rr*18;
    int gy = ytile - 1 + rr, gx = x0 - 1 + xi;
    bool valid = (gy >= 0) & (gy < 32) & (gx >= 0) & (gx < 32);
    int px = gy*32 + gx;
    uint4 v = Z16;
    if (valid){
      if (c < 8)       v = *reinterpret_cast<const uint4*>(xb  + (size_t)px*64 + c*8);
      else if (c < 16) v = *reinterpret_cast<const uint4*>(hb  + (size_t)px*64 + (c-8)*8);
      else if (c < 24) v = *reinterpret_cast<const uint4*>(hlb + (size_t)px*64 + (c-16)*8);
      else if (flag)   v = *reinterpret_cast<const uint4*>(xlb + (size_t)px*64 + (c-24)*8);
    }
    *reinterpret_cast<uint4*>(&bsm[slot*264 + c*8]) = v;
  }
  __syncthreads();

  int w = tid >> 6, lane = tid & 63, lr = lane & 15, lk = lane >> 4;
  int px = nt*16 + lr;
  const int sw = lr & 7;
  const int c0 = ((( 0+lk) ^ sw) << 3);
  const int c1 = ((( 4+lk) ^ sw) << 3);
  const int c2 = ((( 8+lk) ^ sw) << 3);
  const int c3 = (((12+lk) ^ sw) << 3);
  const ushort* aw  = wa_hi + (size_t)(mh*128 + w*16)*128 + lane*8;
  const ushort* awl = wa_lo + (size_t)(mh*128 + w*16)*128 + lane*8;
  ushort* areg = albuf + w*2048;

  float4v acc = {0.f,0.f,0.f,0.f};

  if (!flag){
    #pragma unroll
    for (int k = 0; k < 4; ++k)
      glds16(aw + k*512, areg + k*512);
    #pragma unroll
    for (int p = 0; p < 9; ++p){
      asm volatile("s_waitcnt vmcnt(0)" ::: "memory");
      __builtin_amdgcn_sched_barrier(0);
      short8v A0 = ldfrag(areg + lr*128 + c0);
      short8v A1 = ldfrag(areg + lr*128 + c1);
      short8v A2 = ldfrag(areg + lr*128 + c2);
      short8v A3 = ldfrag(areg + lr*128 + c3);
      int pinl = (p/3)*18 + lr + (p%3);
      const ushort* bl = &bsm[pinl*264 + lk*8];
      short8v BX0 = ldfrag(bl),     BX1 = ldfrag(bl+32);
      short8v BH0 = ldfrag(bl+64),  BH1 = ldfrag(bl+96);
      short8v BL0 = ldfrag(bl+128), BL1 = ldfrag(bl+160);
      acc = __builtin_amdgcn_mfma_f32_16x16x32_bf16(A0, BX0, acc, 0,0,0);
      acc = __builtin_amdgcn_mfma_f32_16x16x32_bf16(A1, BX1, acc, 0,0,0);
      acc = __builtin_amdgcn_mfma_f32_16x16x32_bf16(A2, BH0, acc, 0,0,0);
      acc = __builtin_amdgcn_mfma_f32_16x16x32_bf16(A3, BH1, acc, 0,0,0);
      acc = __builtin_amdgcn_mfma_f32_16x16x32_bf16(A2, BL0, acc, 0,0,0);
      acc = __builtin_amdgcn_mfma_f32_16x16x32_bf16(A3, BL1, acc, 0,0,0);
      if (p < 8){
        __builtin_amdgcn_sched_barrier(0);
        #pragma unroll
        for (int k = 0; k < 4; ++k)
          glds16(aw + (size_t)(p+1)*32768 + k*512, areg + k*512);
      }
    }
  } else {
    #pragma unroll 1
    for (int p = 0; p < 9; ++p){
      int pinl = (p/3)*18 + lr + (p%3);
      const ushort* bl = &bsm[pinl*264 + lk*8];
      short8v BX0 = ldfrag(bl),      BX1 = ldfrag(bl+32);
      short8v BH0 = ldfrag(bl+64),   BH1 = ldfrag(bl+96);
      short8v BL0 = ldfrag(bl+128),  BL1 = ldfrag(bl+160);
      short8v BXl0 = ldfrag(bl+192), BXl1 = ldfrag(bl+224);
      uint4 s0,s1,s2,s3;
      stage_ld(aw + (size_t)p*32768, s0,s1,s2,s3);
      stage_wr(areg + lane*8, s0,s1,s2,s3);
      short8v A0 = ldfrag(areg + lr*128 + c0);
      short8v A1 = ldfrag(areg + lr*128 + c1);
      short8v A2 = ldfrag(areg + lr*128 + c2);
      short8v A3 = ldfrag(areg + lr*128 + c3);
      acc = __builtin_amdgcn_mfma_f32_16x16x32_bf16(A0, BX0, acc, 0,0,0);
      acc = __builtin_amdgcn_mfma_f32_16x16x32_bf16(A1, BX1, acc, 0,0,0);
      acc = __builtin_amdgcn_mfma_f32_16x16x32_bf16(A2, BH0, acc, 0,0,0);
      acc = __builtin_amdgcn_mfma_f32_16x16x32_bf16(A3, BH1, acc, 0,0,0);
      acc = __builtin_amdgcn_mfma_f32_16x16x32_bf16(A2, BL0, acc, 0,0,0);
      acc = __builtin_amdgcn_mfma_f32_16x16x32_bf16(A3, BL1, acc, 0,0,0);
      acc = __builtin_amdgcn_mfma_f32_16x16x32_bf16(A0, BXl0, acc, 0,0,0);
      acc = __builtin_amdgcn_mfma_f32_16x16x32_bf16(A1, BXl1, acc, 0,0,0);
      stage_ld(awl + (size_t)p*32768, s0,s1,s2,s3);
      stage_wr(areg + lane*8, s0,s1,s2,s3);
      short8v Al0 = ldfrag(areg + lr*128 + c0);
      short8v Al1 = ldfrag(areg + lr*128 + c1);
      short8v Al2 = ldfrag(areg + lr*128 + c2);
      short8v Al3 = ldfrag(areg + lr*128 + c3);
      acc = __builtin_amdgcn_mfma_f32_16x16x32_bf16(Al0, BX0, acc, 0,0,0);
      acc = __builtin_amdgcn_mfma_f32_16x16x32_bf16(Al1, BX1, acc, 0,0,0);
      acc = __builtin_amdgcn_mfma_f32_16x16x32_bf16(Al2, BH0, acc, 0,0,0);
      acc = __builtin_amdgcn_mfma_f32_16x16x32_bf16(Al3, BH1, acc, 0,0,0);
    }
  }

  {
    int cc = mh*32 + w*4 + lk;
    int wi = cc*1024 + px;
    size_t sidx = ((size_t)(b*64 + cc))*1024 + px;
    float cprev = cst[sidx];
    float ic = acc[0] + smalls[O_CB + cc];
    float fc = acc[1] + smalls[O_CB + 64 + cc];
    float gc = acc[2] + smalls[O_CB + 128 + cc];
    float oc = acc[3] + smalls[O_CB + 192 + cc];
    float ig = sigm(ic + smalls[O_WCI + wi]*cprev);
    float fg = sigm(fc + smalls[O_WCF + wi]*cprev);
    float cnew = fg*cprev + ig*tanhc(gc);
    float og = sigm(oc + smalls[O_WCO + wi]*cnew);
    cst[sidx]  = cnew;
    hnew[sidx] = og*tanhc(cnew);
  }
}

// ---------------------------------------------------------------------------
// 1x1 projections -> bf16 MFMA-ready buffers — unchanged from R11.
// ---------------------------------------------------------------------------
__global__ __launch_bounds__(256) void k_proj(
  const float* __restrict__ hnew, const float* __restrict__ mst,
  const float* __restrict__ smalls,
  ushort* __restrict__ qb16, ushort* __restrict__ khb16, ushort* __restrict__ kmb16,
  ushort* __restrict__ vth16, ushort* __restrict__ vtm16)
{
  __shared__ float hs[64*9];
  __shared__ float ms[64*9];
  int b = blockIdx.y, n0 = blockIdx.x*8;
  int tid = threadIdx.x, nl = tid&7, rg = tid>>3;
  for (int idx = tid; idx < 512; idx += 256){
    int nn = idx & 7, ch = idx >> 3;
    hs[ch*9+nn] = hnew[((size_t)b*64+ch)*1024 + n0 + nn];
    ms[ch*9+nn] = mst [((size_t)b*64+ch)*1024 + n0 + nn];
  }
  __syncthreads();
  int n = n0 + nl;
  for (int j = 0; j < 6; ++j){
    int r = rg + 32*j;
    if (r >= 176) break;
    const float* src; const float* wrow; float bias;
    int mode, rr;
    if (r < 16)      { mode=0; rr=r;     src = hs; wrow = smalls+O_QW  + rr*64; bias = smalls[O_QB+rr]; }
    else if (r < 32) { mode=1; rr=r-16;  src = hs; wrow = smalls+O_KW  + rr*64; bias = smalls[O_KB+rr]; }
    else if (r < 48) { mode=2; rr=r-32;  src = ms; wrow = smalls+O_K2W + rr*64; bias = smalls[O_K2B+rr]; }
    else if (r < 112){ mode=3; rr=r-48;  src = hs; wrow = smalls+O_VW  + rr*64; bias = smalls[O_VB+rr]; }
    else             { mode=4; rr=r-112; src = ms; wrow = smalls+O_V2W + rr*64; bias = smalls[O_V2B+rr]; }
    float acc = bias;
    #pragma unroll
    for (int c4 = 0; c4 < 16; ++c4){
      float4 w4 = *reinterpret_cast<const float4*>(wrow + c4*4);
      acc += w4.x*src[(c4*4+0)*9+nl] + w4.y*src[(c4*4+1)*9+nl]
           + w4.z*src[(c4*4+2)*9+nl] + w4.w*src[(c4*4+3)*9+nl];
    }
    ushort v = f2bu(acc);
    if (mode <= 2){
      ushort* base = (mode==0) ? qb16 : (mode==1) ? khb16 : kmb16;
      size_t o = ((size_t)b*1024 + n)*32;
      base[o + rr] = v;
      base[o + 16 + rr] = 0;
    } else {
      ushort* base = (mode==3) ? vth16 : vtm16;
      base[((size_t)b*64 + rr)*1024 + n] = v;
    }
  }
}

// ---------------------------------------------------------------------------
// FUSED: MFMA flash attention (both branches) + MFMA zcomb GEMMs + gating.
// grid (64 ntiles of 16, 4 b) = 256 blocks, block 512 = 8 waves.
// Attention: waves 0-3 branch 0, 4-7 branch 1 (as R13).
// zcomb GEMM1: zt = z_w@z + z_b (M=128: wave w rows w*16..; K=128 hi/lo).
// zcomb GEMM2: comb = m_w@[zt;h] + m_b (M=192: m-frags w and w+8(w<4)).
// B operands in LDS as [px][k] bf16 hi/lo; D of GEMM1 written directly in
// B-frag layout. Gating + writes unchanged. LDS ~48.6 KB (time-aliased).
// ---------------------------------------------------------------------------
__global__ __launch_bounds__(512) void k_fattz(
  const ushort* __restrict__ qb16, const ushort* __restrict__ khb16,
  const ushort* __restrict__ kmb16, const ushort* __restrict__ vth16,
  const ushort* __restrict__ vtm16,
  const float* __restrict__ hnew, const float* __restrict__ smalls,
  const ushort* __restrict__ zw16h, const ushort* __restrict__ zw16l,
  const ushort* __restrict__ mw16h, const ushort* __restrict__ mw16l,
  const int* __restrict__ flagp,
  float* __restrict__ mst, ushort* __restrict__ hth, ushort* __restrict__ htl,
  void* __restrict__ outraw, int t)
{
  __shared__ __align__(16) unsigned char poolA[17408]; // es | zb(hi,lo) | ho+mn
  __shared__ __align__(16) ushort ztbh[16*136];
  __shared__ __align__(16) ushort ztbl[16*136];
  __shared__ __align__(16) ushort hlbh[16*72];
  __shared__ __align__(16) ushort hlbl[16*72];
  __shared__ float cb[192*17];
  __shared__ float ml[64*17];
  __shared__ float rs_s[2][4][16];

  ushort* es   = (ushort*)poolA;              // [2][16][272] attn P tiles
  ushort* zbh  = (ushort*)poolA;              // [16][136] after attn
  ushort* zbl  = (ushort*)(poolA + 8704);     // [16][136]
  float*  ho_s = (float*)poolA;               // [64*17] during gating
  float*  mn_s = (float*)(poolA + 4352);      // [64*17]

  int nt = blockIdx.x, b = blockIdx.y;
  int n0 = nt*16;
  int tid = threadIdx.x;
  int w = tid >> 6, lane = tid & 63, lr = lane & 15, lk = lane >> 4;
  int br = w >> 2, wq = w & 3;
  int flag = *flagp;
  const float4v Z4 = {0.f,0.f,0.f,0.f};

  const ushort* kb = (br ? kmb16 : khb16) + (size_t)b*32768;
  const ushort* vt = (br ? vtm16 : vth16) + (size_t)b*65536;
  const ushort* qp = qb16 + (size_t)b*32768;
  ushort* esb = es + br*4352;

  // stage h (bf16 hi/lo transposed) and m (f32) for the zcomb phases
  for (int idx = tid; idx < 1024; idx += 512){
    int ch = idx >> 4, pp = idx & 15;
    float hv = hnew[((size_t)b*64 + ch)*1024 + n0 + pp];
    ushort hh = f2bu(hv);
    hlbh[pp*72 + ch] = hh;
    hlbl[pp*72 + ch] = f2bu(hv - bu2f(hh));
    ml[ch*17+pp] = mst[((size_t)b*64 + ch)*1024 + n0 + pp];
  }

  short8v qf = ldfrag(qp + (size_t)(n0 + lr)*32 + lk*8);

  float4v acc[2];
  acc[0]=Z4; acc[1]=Z4;
  float rsum = 0.f;

  #pragma unroll 1
  for (int mc = 0; mc < 4; ++mc){
    int mbase = mc*256 + wq*64;
    #pragma unroll
    for (int tau = 0; tau < 4; ++tau){
      short8v af = ldfrag(kb + (size_t)(mbase + tau*16 + lr)*32 + lk*8);
      float4v d = __builtin_amdgcn_mfma_f32_16x16x32_bf16(af, qf, Z4, 0,0,0);
      ushort u0 = f2bu(__expf(fminf(d[0], 60.f)));
      ushort u1 = f2bu(__expf(fminf(d[1], 60.f)));
      ushort u2 = f2bu(__expf(fminf(d[2], 60.f)));
      ushort u3 = f2bu(__expf(fminf(d[3], 60.f)));
      rsum += (bu2f(u0) + bu2f(u1)) + (bu2f(u2) + bu2f(u3));
      unsigned lo = (unsigned)u0 | ((unsigned)u1 << 16);
      unsigned hi = (unsigned)u2 | ((unsigned)u3 << 16);
      *reinterpret_cast<uint2*>(&esb[lr*272 + wq*64 + tau*16 + lk*4]) = make_uint2(lo, hi);
    }
    __syncthreads();
    #pragma unroll
    for (int ks = 0; ks < 8; ++ks){
      short8v av = ldfrag(vt + (size_t)(wq*16 + lr)*1024 + mc*256 + ks*32 + lk*8);
      short8v bv = ldfrag(&esb[lr*272 + ks*32 + lk*8]);
      acc[ks & 1] = __builtin_amdgcn_mfma_f32_16x16x32_bf16(av, bv, acc[ks & 1], 0,0,0);
    }
    __syncthreads();
  }

  {
    float r = rsum;
    r += __shfl_xor(r, 16);
    r += __shfl_xor(r, 32);
    if (lane < 16) rs_s[br][wq][lr] = r;
  }
  __syncthreads();   // es dead beyond this point -> zb may overwrite poolA
  {
    float rinv = 1.0f / (rs_s[br][0][lr] + rs_s[br][1][lr] + rs_s[br][2][lr] + rs_s[br][3][lr]);
    int ch0 = br*64 + wq*16 + lk*4;
    ushort uh[4], ul[4];
    #pragma unroll
    for (int r = 0; r < 4; ++r){
      float z = (acc[0][r] + acc[1][r])*rinv;
      uh[r] = f2bu(z);
      ul[r] = f2bu(z - bu2f(uh[r]));
    }
    *reinterpret_cast<uint2*>(&zbh[lr*136 + ch0]) =
      make_uint2((unsigned)uh[0] | ((unsigned)uh[1]<<16), (unsigned)uh[2] | ((unsigned)uh[3]<<16));
    *reinterpret_cast<uint2*>(&zbl[lr*136 + ch0]) =
      make_uint2((unsigned)ul[0] | ((unsigned)ul[1]<<16), (unsigned)ul[2] | ((unsigned)ul[3]<<16));
  }
  __syncthreads();

  // ---------------- GEMM1: zt = z_w @ z + z_b (M=128, K=128) ----------------
  {
    float4v zacc = Z4;
    if (!flag){
      #pragma unroll
      for (int kf = 0; kf < 4; ++kf){
        short8v a  = ldfrag(zw16h + (size_t)(w*16 + lr)*128 + kf*32 + lk*8);
        short8v bh = ldfrag(&zbh[lr*136 + kf*32 + lk*8]);
        short8v bl = ldfrag(&zbl[lr*136 + kf*32 + lk*8]);
        zacc = __builtin_amdgcn_mfma_f32_16x16x32_bf16(a, bh, zacc, 0,0,0);
        zacc = __builtin_amdgcn_mfma_f32_16x16x32_bf16(a, bl, zacc, 0,0,0);
      }
    } else {
      #pragma unroll
      for (int kf = 0; kf < 4; ++kf){
        short8v a  = ldfrag(zw16h + (size_t)(w*16 + lr)*128 + kf*32 + lk*8);
        short8v al = ldfrag(zw16l + (size_t)(w*16 + lr)*128 + kf*32 + lk*8);
        short8v bh = ldfrag(&zbh[lr*136 + kf*32 + lk*8]);
        short8v bl = ldfrag(&zbl[lr*136 + kf*32 + lk*8]);
        zacc = __builtin_amdgcn_mfma_f32_16x16x32_bf16(a,  bh, zacc, 0,0,0);
        zacc = __builtin_amdgcn_mfma_f32_16x16x32_bf16(a,  bl, zacc, 0,0,0);
        zacc = __builtin_amdgcn_mfma_f32_16x16x32_bf16(al, bh, zacc, 0,0,0);
      }
    }
    int r0 = w*16 + lk*4;
    ushort th[4], tl[4];
    #pragma unroll
    for (int q = 0; q < 4; ++q){
      float ztv = zacc[q] + smalls[O_ZB + r0 + q];
      th[q] = f2bu(ztv);
      tl[q] = f2bu(ztv - bu2f(th[q]));
    }
    *reinterpret_cast<uint2*>(&ztbh[lr*136 + r0]) =
      make_uint2((unsigned)th[0] | ((unsigned)th[1]<<16), (unsigned)th[2] | ((unsigned)th[3]<<16));
    *reinterpret_cast<uint2*>(&ztbl[lr*136 + r0]) =
      make_uint2((unsigned)tl[0] | ((unsigned)tl[1]<<16), (unsigned)tl[2] | ((unsigned)tl[3]<<16));
  }
  __syncthreads();

  // ------- GEMM2: comb = m_w @ [zt; h] + m_b (M=192, K=192) -------
  #pragma unroll
  for (int mi = 0; mi < 2; ++mi){
    if (mi == 1 && w >= 4) break;
    int mf = (mi == 0) ? w : (w + 8);
    float4v cacc = Z4;
    const ushort* arow  = mw16h + (size_t)(mf*16 + lr)*192;
    const ushort* arowl = mw16l + (size_t)(mf*16 + lr)*192;
    if (!flag){
      #pragma unroll
      for (int kf = 0; kf < 4; ++kf){
        short8v a  = ldfrag(arow + kf*32 + lk*8);
        short8v bh = ldfrag(&ztbh[lr*136 + kf*32 + lk*8]);
        short8v bl = ldfrag(&ztbl[lr*136 + kf*32 + lk*8]);
        cacc = __builtin_amdgcn_mfma_f32_16x16x32_bf16(a, bh, cacc, 0,0,0);
        cacc = __builtin_amdgcn_mfma_f32_16x16x32_bf16(a, bl, cacc, 0,0,0);
      }
      #pragma unroll
      for (int kf = 0; kf < 2; ++kf){
        short8v a  = ldfrag(arow + 128 + kf*32 + lk*8);
        short8v bh = ldfrag(&hlbh[lr*72 + kf*32 + lk*8]);
        short8v bl = ldfrag(&hlbl[lr*72 + kf*32 + lk*8]);
        cacc = __builtin_amdgcn_mfma_f32_16x16x32_bf16(a, bh, cacc, 0,0,0);
        cacc = __builtin_amdgcn_mfma_f32_16x16x32_bf16(a, bl, cacc, 0,0,0);
      }
    } else {
      #pragma unroll
      for (int kf = 0; kf < 4; ++kf){
        short8v a  = ldfrag(arow + kf*32 + lk*8);
        short8v al = ldfrag(arowl + kf*32 + lk*8);
        short8v bh = ldfrag(&ztbh[lr*136 + kf*32 + lk*8]);
        short8v bl = ldfrag(&ztbl[lr*136 + kf*32 + lk*8]);
        cacc = __builtin_amdgcn_mfma_f32_16x16x32_bf16(a,  bh, cacc, 0,0,0);
        cacc = __builtin_amdgcn_mfma_f32_16x16x32_bf16(a,  bl, cacc, 0,0,0);
        cacc = __builtin_amdgcn_mfma_f32_16x16x32_bf16(al, bh, cacc, 0,0,0);
      }
      #pragma unroll
      for (int kf = 0; kf < 2; ++kf){
        short8v a  = ldfrag(arow + 128 + kf*32 + lk*8);
        short8v al = ldfrag(arowl + 128 + kf*32 + lk*8);
        short8v bh = ldfrag(&hlbh[lr*72 + kf*32 + lk*8]);
        short8v bl = ldfrag(&hlbl[lr*72 + kf*32 + lk*8]);
        cacc = __builtin_amdgcn_mfma_f32_16x16x32_bf16(a,  bh, cacc, 0,0,0);
        cacc = __builtin_amdgcn_mfma_f32_16x16x32_bf16(a,  bl, cacc, 0,0,0);
        cacc = __builtin_amdgcn_mfma_f32_16x16x32_bf16(al, bh, cacc, 0,0,0);
      }
    }
    int r0 = mf*16 + lk*4;
    #pragma unroll
    for (int q = 0; q < 4; ++q)
      cb[(r0+q)*17 + lr] = cacc[q] + smalls[O_MB + r0 + q];
  }
  __syncthreads();

  // ---------------- gating (16 px, 512 threads) ----------------
  {
    int px = tid >> 5, lr2 = tid & 31;
    #pragma unroll
    for (int j = 0; j < 2; ++j){
      int ch = lr2 + 32*j;
      float mo = cb[ch*17 + px];
      float mg = cb[(64+ch)*17 + px];
      float mi = cb[(128+ch)*17 + px];
      float mold = ml[ch*17 + px];
      float gi = sigm(mi);
      float mnew = (1.0f-gi)*mold + gi*tanhc(mg);
      float ho = sigm(mo)*mnew;
      ho_s[ch*17+px] = ho;
      mn_s[ch*17+px] = mnew;
    }
  }
  __syncthreads();
  for (int idx = tid; idx < 1024; idx += 512){
    int ch = idx >> 4, pp = idx & 15;
    int n = n0 + pp;
    size_t gidx = ((size_t)b*64 + ch)*1024 + n;
    mst[gidx] = mn_s[ch*17+pp];
    float ho = ho_s[ch*17+pp];
    size_t tix = ((size_t)b*1024 + n)*64 + ch;
    ushort hb_ = f2bu(ho);
    hth[tix] = hb_;
    htl[tix] = f2bu(ho - bu2f(hb_));
    size_t oidx = ((size_t)(b*64+ch)*8 + t)*1024 + n;
    if (flag) ((float*)outraw)[oidx] = ho;
    else      ((bf16*)outraw)[oidx] = __float2bfloat16(ho);
  }
}

extern "C" void kernel_launch(void* const* d_in, const int* in_sizes, int n_in,
                              void* d_out, int out_size, void* d_ws, size_t ws_size,
                              hipStream_t stream)
{
  float* ws = (float*)d_ws;
  int* flag = (int*)(ws + WS_FLAG);
  float* c    = ws + WS_C;
  float* m    = ws + WS_M;
  float* hnew = ws + WS_HNEW;
  ushort* qb16  = (ushort*)(ws + WS_QB16);
  ushort* khb16 = (ushort*)(ws + WS_KHB16);
  ushort* kmb16 = (ushort*)(ws + WS_KMB16);
  ushort* vth16 = (ushort*)(ws + WS_VTH16);
  ushort* vtm16 = (ushort*)(ws + WS_VTM16);
  ushort* zw16h = (ushort*)(ws + WS_ZW16H);
  ushort* zw16l = (ushort*)(ws + WS_ZW16L);
  ushort* mw16h = (ushort*)(ws + WS_MW16H);
  ushort* mw16l = (ushort*)(ws + WS_MW16L);
  ushort* wa_hi = (ushort*)(ws + WS_WAHI);
  ushort* wa_lo = (ushort*)(ws + WS_WALO);
  ushort* xt_hi = (ushort*)(ws + WS_XTHI);
  ushort* xt_lo = (ushort*)(ws + WS_XTLO);
  ushort* ht_hi = (ushort*)(ws + WS_HTHI);
  ushort* ht_lo = (ushort*)(ws + WS_HTLO);

  k_probe<<<1, 256, 0, stream>>>((const unsigned int*)d_in[0], flag);
  P18 pk;
  for (int i = 0; i < 18; ++i) pk.p[i] = d_in[2 + i];
  k_wconv<<<dim3(64,18), 256, 0, stream>>>(pk, flag, ws);
  k_init<<<3072, 256, 0, stream>>>(d_in[1], flag, ws);
  k_xt<<<dim3(16,32), 256, 0, stream>>>(d_in[0], flag, ws);
  k_wtrans<<<144, 256, 0, stream>>>(ws);

  for (int t = 0; t < 8; ++t){
    k_conv_mfma<<<dim3(64,2,4), 512, 0, stream>>>(flag, wa_hi, wa_lo, xt_hi, xt_lo,
                                                  ht_hi, ht_lo, ws, c, hnew, t);
    k_proj<<<dim3(128,4), 256, 0, stream>>>(hnew, m, ws, qb16, khb16, kmb16, vth16, vtm16);
    k_fattz<<<dim3(64,4), 512, 0, stream>>>(qb16, khb16, kmb16, vth16, vtm16,
                                            hnew, ws, zw16h, zw16l, mw16h, mw16l, flag,
                                            m, ht_hi, ht_lo, d_out, t);
  }
  (void)in_sizes; (void)n_in; (void)out_size; (void)ws_size;
}

// Round 15
// 457.917 us; speedup vs baseline: 1.9184x; 1.1062x over previous
//
#include <hip/hip_runtime.h>
#include <hip/hip_bf16.h>

typedef __hip_bfloat16 bf16;
typedef unsigned short ushort;
typedef __attribute__((ext_vector_type(8))) short short8v;   // 8 bf16 = 4 VGPR
typedef __attribute__((ext_vector_type(4))) float float4v;

__device__ __forceinline__ float b2f(bf16 v){ return __bfloat162float(v); }
__device__ __forceinline__ float sigm(float x){ return 1.0f/(1.0f+__expf(-x)); }
__device__ __forceinline__ float tanhc(float x){
  x = fminf(15.0f, fmaxf(-15.0f, x));
  float e = __expf(2.0f*x);
  return (e-1.0f)/(e+1.0f);
}
__device__ __forceinline__ ushort f2bu(float f){
  bf16 h = __float2bfloat16(f); return *reinterpret_cast<ushort*>(&h);
}
__device__ __forceinline__ float bu2f(ushort u){
  return __uint_as_float(((unsigned)u)<<16);
}
__device__ __forceinline__ short8v ldfrag(const ushort* p){
  return *reinterpret_cast<const short8v*>(p);
}
// direct global->LDS DMA, 16B per lane; lds dst = uniform base + lane*16
__device__ __forceinline__ void glds16(const ushort* g, ushort* l){
  __builtin_amdgcn_global_load_lds(
    (const __attribute__((address_space(1))) unsigned int*)g,
    (__attribute__((address_space(3))) unsigned int*)l, 16, 0, 0);
}
__device__ __forceinline__ void stage_ld(const ushort* s, uint4& a0, uint4& a1,
                                         uint4& a2, uint4& a3){
  a0 = *reinterpret_cast<const uint4*>(s);
  a1 = *reinterpret_cast<const uint4*>(s+512);
  a2 = *reinterpret_cast<const uint4*>(s+1024);
  a3 = *reinterpret_cast<const uint4*>(s+1536);
}
__device__ __forceinline__ void stage_wr(ushort* d, uint4 a0, uint4 a1,
                                         uint4 a2, uint4 a3){
  *reinterpret_cast<uint4*>(d)      = a0;
  *reinterpret_cast<uint4*>(d+512)  = a1;
  *reinterpret_cast<uint4*>(d+1024) = a2;
  *reinterpret_cast<uint4*>(d+1536) = a3;
}

// ---------------------------------------------------------------------------
// ws layout (float offsets)
// ---------------------------------------------------------------------------
#define WS_SMALL   0
#define WS_FLAG    262144
#define WS_ZROW    262160
#define WS_H       262208
#define WS_C       524352
#define WS_M       786496
#define WS_HNEW    1048640     // dead (f32 hnew no longer used)
#define WS_QB16    1310784
#define WS_KHB16   1376320
#define WS_KMB16   1441856
#define WS_VTH16   1507392
#define WS_VTM16   1638464
#define WS_MTH     1769536     // 131072 f  mT[b][px][64] bf16 hi
#define WS_MTL     1900608     // 131072 f
#define WS_HNTH    2031680     // 131072 f  hnT[b][px][64] bf16 hi
#define WS_HNTL    2162752     // 131072 f
#define WS_ZW16H   2293824
#define WS_ZW16L   2302016
#define WS_MW16H   2310208
#define WS_MW16L   2328640
#define WS_WAHI    2347072
#define WS_WALO    2494528
#define WS_XTHI    2641984
#define WS_XTLO    3690560
#define WS_HTHI    4739136
#define WS_HTLO    4870208
#define WS_PWH     5001280     // 5632 f  proj weights [176][64] bf16 hi
#define WS_PWL     5006912     // 5632 f
// small-weight offsets inside WS_SMALL
#define O_CB    0
#define O_WCI   256
#define O_WCF   65792
#define O_WCO   131328
#define O_QW    196864
#define O_QB    197888
#define O_KW    197904
#define O_KB    198928
#define O_K2W   198944
#define O_K2B   199968
#define O_VW    199984
#define O_VB    204080
#define O_V2W   204144
#define O_V2B   208240
#define O_ZW    208304
#define O_ZB    224688
#define O_MW    224816
#define O_MB    261680

// ---------------------------------------------------------------------------
// dtype probe (f32 vs bf16 input data)
// ---------------------------------------------------------------------------
__global__ void k_probe(const unsigned int* __restrict__ Xu, int* __restrict__ flag){
  __shared__ int cnt;
  if (threadIdx.x == 0) cnt = 0;
  __syncthreads();
  unsigned int u = Xu[threadIdx.x];
  float f = __uint_as_float((u & 0xffffu) << 16);
  int bad = (fabsf(f) <= 1e4f) ? 0 : 1;
  atomicAdd(&cnt, bad);
  __syncthreads();
  if (threadIdx.x == 0) *flag = (cnt > 16) ? 1 : 0;
}

// ---------------------------------------------------------------------------
// convert the 18 small inputs into f32 copies in ws
// ---------------------------------------------------------------------------
struct P18 { const void* p[18]; };

__global__ __launch_bounds__(256) void k_wconv(P18 pk, const int* __restrict__ flagp,
                                               float* __restrict__ dst){
  const int ns[18]   = {256,65536,65536,65536,1024,16,1024,16,1024,16,
                        4096,64,4096,64,16384,128,36864,192};
  const int offs[18] = {O_CB,O_WCI,O_WCF,O_WCO,O_QW,O_QB,O_KW,O_KB,O_K2W,O_K2B,
                        O_VW,O_VB,O_V2W,O_V2B,O_ZW,O_ZB,O_MW,O_MB};
  int y = blockIdx.y;
  int n = ns[y];
  int flag = *flagp;
  const void* src = pk.p[y];
  for (int i = blockIdx.x*256 + threadIdx.x; i < n; i += gridDim.x*256){
    float v = flag ? ((const float*)src)[i] : b2f(((const bf16*)src)[i]);
    dst[offs[y] + i] = v;
  }
}

// bf16 hi/lo copies: z_w (128x128), m_w (192x192), proj weights [176][64]
__global__ __launch_bounds__(256) void k_wtrans(float* __restrict__ ws){
  int i = blockIdx.x*256 + threadIdx.x;
  if (i < 16384){
    float f = ws[O_ZW + i];
    ushort h = f2bu(f);
    ((ushort*)(ws + WS_ZW16H))[i] = h;
    ((ushort*)(ws + WS_ZW16L))[i] = f2bu(f - bu2f(h));
  }
  if (i < 36864){
    float f = ws[O_MW + i];
    ushort h = f2bu(f);
    ((ushort*)(ws + WS_MW16H))[i] = h;
    ((ushort*)(ws + WS_MW16L))[i] = f2bu(f - bu2f(h));
  }
  if (i < 11264){
    int r = i >> 6, k = i & 63;
    float f;
    if (r < 16)       f = ws[O_QW  + r*64 + k];
    else if (r < 32)  f = ws[O_KW  + (r-16)*64 + k];
    else if (r < 48)  f = ws[O_K2W + (r-32)*64 + k];
    else if (r < 112) f = ws[O_VW  + (r-48)*64 + k];
    else              f = ws[O_V2W + (r-112)*64 + k];
    ushort h = f2bu(f);
    ((ushort*)(ws + WS_PWH))[i] = h;
    ((ushort*)(ws + WS_PWL))[i] = f2bu(f - bu2f(h));
  }
}

// ---------------------------------------------------------------------------
// init: zero states + hT + mT + q/k pad regions; build conv wA (hi/lo),
// CHUNK-SWIZZLED: 16B-chunk c of row m stored at chunk (c ^ (m&7)).
// ---------------------------------------------------------------------------
__global__ __launch_bounds__(256) void k_init(const void* __restrict__ conv_w,
                                              const int* __restrict__ flagp,
                                              float* __restrict__ ws){
  int i = blockIdx.x*256 + threadIdx.x;
  int flag = *flagp;
  if (i < 786432) ws[WS_H + i] = 0.0f;
  if (i < 32) ws[WS_ZROW + i] = 0.0f;
  if (i < 196608) ((unsigned*)(ws + WS_QB16))[i] = 0u;   // qb/kh/km incl. pad
  if (i < 294912){
    int ci = i & 127;
    int j = i >> 7;           // j = p*256 + mm
    int mm = j & 255, p = j >> 8;
    int cc = mm >> 2, g = mm & 3;
    int si = ((g*64 + cc)*128 + ci)*9 + p;
    int cis = ((((ci >> 3) ^ (mm & 7)) << 3) | (ci & 7));
    int di = (j << 7) + cis;
    ushort* wah = (ushort*)(ws + WS_WAHI);
    ushort* wal = (ushort*)(ws + WS_WALO);
    if (flag){
      float f = ((const float*)conv_w)[si];
      ushort hi = f2bu(f);
      wah[di] = hi;
      wal[di] = f2bu(f - bu2f(hi));
    } else {
      wah[di] = ((const ushort*)conv_w)[si];
    }
  }
  if (i < 131072){
    ((unsigned*)(ws + WS_HTHI))[i] = 0u;
    ((unsigned*)(ws + WS_HTLO))[i] = 0u;
    ((unsigned*)(ws + WS_MTH))[i] = 0u;
    ((unsigned*)(ws + WS_MTL))[i] = 0u;
  }
}

// ---------------------------------------------------------------------------
// X transpose: XT[b][t][px][ci]
// ---------------------------------------------------------------------------
__global__ __launch_bounds__(256) void k_xt(const void* __restrict__ Xraw,
                                            const int* __restrict__ flagp,
                                            float* __restrict__ ws){
  __shared__ ushort hi_s[64][66];
  __shared__ ushort lo_s[64][66];
  int pt = blockIdx.x, s = blockIdx.y;
  int b = s >> 3, t = s & 7;
  int flag = *flagp;
  int tid = threadIdx.x;
  for (int k = 0; k < 16; ++k){
    int idx = tid + k*256;
    int ci = idx >> 6, pxl = idx & 63;
    size_t si = ((size_t)(b*64 + ci)*8 + t)*1024 + pt*64 + pxl;
    if (flag){
      float f = ((const float*)Xraw)[si];
      ushort h = f2bu(f);
      hi_s[pxl][ci] = h;
      lo_s[pxl][ci] = f2bu(f - bu2f(h));
    } else {
      hi_s[pxl][ci] = ((const ushort*)Xraw)[si];
    }
  }
  __syncthreads();
  ushort* xh = (ushort*)(ws + WS_XTHI) + ((size_t)s*1024 + pt*64)*64;
  ushort* xl = (ushort*)(ws + WS_XTLO) + ((size_t)s*1024 + pt*64)*64;
  for (int k = 0; k < 16; ++k){
    int idx = tid + k*256;
    int pxl = idx >> 6, ci = idx & 63;
    xh[pxl*64 + ci] = hi_s[pxl][ci];
    if (flag) xl[pxl*64 + ci] = lo_s[pxl][ci];
  }
}

// ---------------------------------------------------------------------------
// conv 3x3 + peephole LSTM via MFMA implicit GEMM (R11 structure).
// Epilogue now emits hnT bf16 hi/lo (proj/fattz B-operand) instead of f32.
// ---------------------------------------------------------------------------
__global__ __launch_bounds__(512, 4) void k_conv_mfma(
  const int* __restrict__ flagp,
  const ushort* __restrict__ wa_hi, const ushort* __restrict__ wa_lo,
  const ushort* __restrict__ xt_hi, const ushort* __restrict__ xt_lo,
  const ushort* __restrict__ ht_hi, const ushort* __restrict__ ht_lo,
  const float* __restrict__ smalls, float* __restrict__ cst,
  ushort* __restrict__ hnth, ushort* __restrict__ hntl, int t)
{
  __shared__ ushort albuf[16384];
  __shared__ ushort bsm[54*264];
  int nt = blockIdx.x, mh = blockIdx.y, b = blockIdx.z;
  int tid = threadIdx.x;
  int flag = *flagp;
  int ytile = nt >> 1, x0 = (nt & 1) * 16;

  const ushort* xb  = xt_hi + ((size_t)(b*8 + t))*65536;
  const ushort* xlb = xt_lo + ((size_t)(b*8 + t))*65536;
  const ushort* hb  = ht_hi + (size_t)b*65536;
  const ushort* hlb = ht_lo + (size_t)b*65536;

  const uint4 Z16 = make_uint4(0,0,0,0);
  for (int idx = tid; idx < 1728; idx += 512){
    int slot = idx >> 5, c = idx & 31;
    int rr = slot / 18, xi = slot - rr*18;
    int gy = ytile - 1 + rr, gx = x0 - 1 + xi;
    bool valid = (gy >= 0) & (gy < 32) & (gx >= 0) & (gx < 32);
    int px = gy*32 + gx;
    uint4 v = Z16;
    if (valid){
      if (c < 8)       v = *reinterpret_cast<const uint4*>(xb  + (size_t)px*64 + c*8);
      else if (c < 16) v = *reinterpret_cast<const uint4*>(hb  + (size_t)px*64 + (c-8)*8);
      else if (c < 24) v = *reinterpret_cast<const uint4*>(hlb + (size_t)px*64 + (c-16)*8);
      else if (flag)   v = *reinterpret_cast<const uint4*>(xlb + (size_t)px*64 + (c-24)*8);
    }
    *reinterpret_cast<uint4*>(&bsm[slot*264 + c*8]) = v;
  }
  __syncthreads();

  int w = tid >> 6, lane = tid & 63, lr = lane & 15, lk = lane >> 4;
  int px = nt*16 + lr;
  const int sw = lr & 7;
  const int c0 = ((( 0+lk) ^ sw) << 3);
  const int c1 = ((( 4+lk) ^ sw) << 3);
  const int c2 = ((( 8+lk) ^ sw) << 3);
  const int c3 = (((12+lk) ^ sw) << 3);
  const ushort* aw  = wa_hi + (size_t)(mh*128 + w*16)*128 + lane*8;
  const ushort* awl = wa_lo + (size_t)(mh*128 + w*16)*128 + lane*8;
  ushort* areg = albuf + w*2048;

  float4v acc = {0.f,0.f,0.f,0.f};

  if (!flag){
    #pragma unroll
    for (int k = 0; k < 4; ++k)
      glds16(aw + k*512, areg + k*512);
    #pragma unroll
    for (int p = 0; p < 9; ++p){
      asm volatile("s_waitcnt vmcnt(0)" ::: "memory");
      __builtin_amdgcn_sched_barrier(0);
      short8v A0 = ldfrag(areg + lr*128 + c0);
      short8v A1 = ldfrag(areg + lr*128 + c1);
      short8v A2 = ldfrag(areg + lr*128 + c2);
      short8v A3 = ldfrag(areg + lr*128 + c3);
      int pinl = (p/3)*18 + lr + (p%3);
      const ushort* bl = &bsm[pinl*264 + lk*8];
      short8v BX0 = ldfrag(bl),     BX1 = ldfrag(bl+32);
      short8v BH0 = ldfrag(bl+64),  BH1 = ldfrag(bl+96);
      short8v BL0 = ldfrag(bl+128), BL1 = ldfrag(bl+160);
      acc = __builtin_amdgcn_mfma_f32_16x16x32_bf16(A0, BX0, acc, 0,0,0);
      acc = __builtin_amdgcn_mfma_f32_16x16x32_bf16(A1, BX1, acc, 0,0,0);
      acc = __builtin_amdgcn_mfma_f32_16x16x32_bf16(A2, BH0, acc, 0,0,0);
      acc = __builtin_amdgcn_mfma_f32_16x16x32_bf16(A3, BH1, acc, 0,0,0);
      acc = __builtin_amdgcn_mfma_f32_16x16x32_bf16(A2, BL0, acc, 0,0,0);
      acc = __builtin_amdgcn_mfma_f32_16x16x32_bf16(A3, BL1, acc, 0,0,0);
      if (p < 8){
        __builtin_amdgcn_sched_barrier(0);
        #pragma unroll
        for (int k = 0; k < 4; ++k)
          glds16(aw + (size_t)(p+1)*32768 + k*512, areg + k*512);
      }
    }
  } else {
    #pragma unroll 1
    for (int p = 0; p < 9; ++p){
      int pinl = (p/3)*18 + lr + (p%3);
      const ushort* bl = &bsm[pinl*264 + lk*8];
      short8v BX0 = ldfrag(bl),      BX1 = ldfrag(bl+32);
      short8v BH0 = ldfrag(bl+64),   BH1 = ldfrag(bl+96);
      short8v BL0 = ldfrag(bl+128),  BL1 = ldfrag(bl+160);
      short8v BXl0 = ldfrag(bl+192), BXl1 = ldfrag(bl+224);
      uint4 s0,s1,s2,s3;
      stage_ld(aw + (size_t)p*32768, s0,s1,s2,s3);
      stage_wr(areg + lane*8, s0,s1,s2,s3);
      short8v A0 = ldfrag(areg + lr*128 + c0);
      short8v A1 = ldfrag(areg + lr*128 + c1);
      short8v A2 = ldfrag(areg + lr*128 + c2);
      short8v A3 = ldfrag(areg + lr*128 + c3);
      acc = __builtin_amdgcn_mfma_f32_16x16x32_bf16(A0, BX0, acc, 0,0,0);
      acc = __builtin_amdgcn_mfma_f32_16x16x32_bf16(A1, BX1, acc, 0,0,0);
      acc = __builtin_amdgcn_mfma_f32_16x16x32_bf16(A2, BH0, acc, 0,0,0);
      acc = __builtin_amdgcn_mfma_f32_16x16x32_bf16(A3, BH1, acc, 0,0,0);
      acc = __builtin_amdgcn_mfma_f32_16x16x32_bf16(A2, BL0, acc, 0,0,0);
      acc = __builtin_amdgcn_mfma_f32_16x16x32_bf16(A3, BL1, acc, 0,0,0);
      acc = __builtin_amdgcn_mfma_f32_16x16x32_bf16(A0, BXl0, acc, 0,0,0);
      acc = __builtin_amdgcn_mfma_f32_16x16x32_bf16(A1, BXl1, acc, 0,0,0);
      stage_ld(awl + (size_t)p*32768, s0,s1,s2,s3);
      stage_wr(areg + lane*8, s0,s1,s2,s3);
      short8v Al0 = ldfrag(areg + lr*128 + c0);
      short8v Al1 = ldfrag(areg + lr*128 + c1);
      short8v Al2 = ldfrag(areg + lr*128 + c2);
      short8v Al3 = ldfrag(areg + lr*128 + c3);
      acc = __builtin_amdgcn_mfma_f32_16x16x32_bf16(Al0, BX0, acc, 0,0,0);
      acc = __builtin_amdgcn_mfma_f32_16x16x32_bf16(Al1, BX1, acc, 0,0,0);
      acc = __builtin_amdgcn_mfma_f32_16x16x32_bf16(Al2, BH0, acc, 0,0,0);
      acc = __builtin_amdgcn_mfma_f32_16x16x32_bf16(Al3, BH1, acc, 0,0,0);
    }
  }

  {
    int cc = mh*32 + w*4 + lk;
    int wi = cc*1024 + px;
    size_t sidx = ((size_t)(b*64 + cc))*1024 + px;
    float cprev = cst[sidx];
    float ic = acc[0] + smalls[O_CB + cc];
    float fc = acc[1] + smalls[O_CB + 64 + cc];
    float gc = acc[2] + smalls[O_CB + 128 + cc];
    float oc = acc[3] + smalls[O_CB + 192 + cc];
    float ig = sigm(ic + smalls[O_WCI + wi]*cprev);
    float fg = sigm(fc + smalls[O_WCF + wi]*cprev);
    float cnew = fg*cprev + ig*tanhc(gc);
    float og = sigm(oc + smalls[O_WCO + wi]*cnew);
    cst[sidx] = cnew;
    float hv = og*tanhc(cnew);
    size_t tix = ((size_t)b*1024 + px)*64 + cc;
    ushort hh = f2bu(hv);
    hnth[tix] = hh;
    hntl[tix] = f2bu(hv - bu2f(hh));
  }
}

// ---------------------------------------------------------------------------
// MFMA projections: q,kh (h), km (m), vh (h), vm (m).
// grid (64 nt of 16 px, 4 b) = 256 blocks, block 256 = 4 waves.
// 11 tiles (16 rows each): wave 0 {q,kh,km}, 1 {vh0-2}, 2 {vh3,vm0,vm1},
// 3 {vm2,vm3}. A = exact-bf16 weights pw[176][64]; B = hnT/mT hi+lo frags
// read directly from global. D: col=px-local, row=lk*4+q.
// ---------------------------------------------------------------------------
__global__ __launch_bounds__(256) void k_projm(
  const ushort* __restrict__ hnth, const ushort* __restrict__ hntl,
  const ushort* __restrict__ mth, const ushort* __restrict__ mtl,
  const ushort* __restrict__ pwh, const ushort* __restrict__ pwl,
  const float* __restrict__ smalls, const int* __restrict__ flagp,
  ushort* __restrict__ qb16, ushort* __restrict__ khb16, ushort* __restrict__ kmb16,
  ushort* __restrict__ vth16, ushort* __restrict__ vtm16)
{
  int nt = blockIdx.x, b = blockIdx.y;
  int n0 = nt*16;
  int tid = threadIdx.x;
  int w = tid >> 6, lane = tid & 63, lr = lane & 15, lk = lane >> 4;
  int flag = *flagp;
  const float4v Z4 = {0.f,0.f,0.f,0.f};
  size_t bb = ((size_t)b*1024 + n0 + lr)*64 + lk*8;
  short8v BH0  = ldfrag(hnth + bb), BH1  = ldfrag(hnth + bb + 32);
  short8v BHl0 = ldfrag(hntl + bb), BHl1 = ldfrag(hntl + bb + 32);
  short8v BM0  = ldfrag(mth + bb),  BM1  = ldfrag(mth + bb + 32);
  short8v BMl0 = ldfrag(mtl + bb),  BMl1 = ldfrag(mtl + bb + 32);
  int n = n0 + lr;
  int tstart = w*3;                       // w=3 -> 9
  int tcnt = (w == 3) ? 2 : 3;
  for (int ti = 0; ti < tcnt; ++ti){
    int tt = tstart + ti;
    const ushort* ar = pwh + (size_t)(tt*16 + lr)*64 + lk*8;
    short8v a0 = ldfrag(ar), a1 = ldfrag(ar + 32);
    bool srcm = (tt == 2) || (tt >= 7);
    short8v b0  = srcm ? BM0  : BH0,  b1  = srcm ? BM1  : BH1;
    short8v bl0 = srcm ? BMl0 : BHl0, bl1 = srcm ? BMl1 : BHl1;
    float4v d = Z4;
    d = __builtin_amdgcn_mfma_f32_16x16x32_bf16(a0, b0,  d, 0,0,0);
    d = __builtin_amdgcn_mfma_f32_16x16x32_bf16(a1, b1,  d, 0,0,0);
    d = __builtin_amdgcn_mfma_f32_16x16x32_bf16(a0, bl0, d, 0,0,0);
    d = __builtin_amdgcn_mfma_f32_16x16x32_bf16(a1, bl1, d, 0,0,0);
    if (flag){
      const ushort* arl = pwl + (size_t)(tt*16 + lr)*64 + lk*8;
      short8v al0 = ldfrag(arl), al1 = ldfrag(arl + 32);
      d = __builtin_amdgcn_mfma_f32_16x16x32_bf16(al0, b0, d, 0,0,0);
      d = __builtin_amdgcn_mfma_f32_16x16x32_bf16(al1, b1, d, 0,0,0);
    }
    int boff = (tt==0) ? O_QB : (tt==1) ? O_KB : (tt==2) ? O_K2B
             : (tt<7) ? (O_VB + (tt-3)*16) : (O_V2B + (tt-7)*16);
    if (tt < 3){
      ushort* base = (tt==0) ? qb16 : (tt==1) ? khb16 : kmb16;
      ushort u[4];
      #pragma unroll
      for (int q = 0; q < 4; ++q)
        u[q] = f2bu(d[q] + smalls[boff + lk*4 + q]);
      *reinterpret_cast<uint2*>(&base[((size_t)b*1024 + n)*32 + lk*4]) =
        make_uint2((unsigned)u[0] | ((unsigned)u[1]<<16),
                   (unsigned)u[2] | ((unsigned)u[3]<<16));
    } else {
      ushort* base = (tt<7) ? vth16 : vtm16;
      int cc0 = ((tt<7) ? (tt-3) : (tt-7))*16 + lk*4;
      #pragma unroll
      for (int q = 0; q < 4; ++q)
        base[((size_t)b*64 + cc0 + q)*1024 + n] = f2bu(d[q] + smalls[boff + lk*4 + q]);
    }
  }
}

// ---------------------------------------------------------------------------
// FUSED: MFMA flash attention (both branches) + MFMA zcomb GEMMs + gating.
// GEMM2 h-operand read directly from global hnT; emits mT bf16 hi/lo.
// ---------------------------------------------------------------------------
__global__ __launch_bounds__(512) void k_fattz(
  const ushort* __restrict__ qb16, const ushort* __restrict__ khb16,
  const ushort* __restrict__ kmb16, const ushort* __restrict__ vth16,
  const ushort* __restrict__ vtm16,
  const ushort* __restrict__ hnth, const ushort* __restrict__ hntl,
  const float* __restrict__ smalls,
  const ushort* __restrict__ zw16h, const ushort* __restrict__ zw16l,
  const ushort* __restrict__ mw16h, const ushort* __restrict__ mw16l,
  const int* __restrict__ flagp,
  float* __restrict__ mst, ushort* __restrict__ mth, ushort* __restrict__ mtl,
  ushort* __restrict__ hth, ushort* __restrict__ htl,
  void* __restrict__ outraw, int t)
{
  __shared__ __align__(16) unsigned char poolA[17408]; // es | zb(hi,lo) | ho+mn
  __shared__ __align__(16) ushort ztbh[16*136];
  __shared__ __align__(16) ushort ztbl[16*136];
  __shared__ float cb[192*17];
  __shared__ float ml[64*17];
  __shared__ float rs_s[2][4][16];

  ushort* es   = (ushort*)poolA;
  ushort* zbh  = (ushort*)poolA;
  ushort* zbl  = (ushort*)(poolA + 8704);
  float*  ho_s = (float*)poolA;
  float*  mn_s = (float*)(poolA + 4352);

  int nt = blockIdx.x, b = blockIdx.y;
  int n0 = nt*16;
  int tid = threadIdx.x;
  int w = tid >> 6, lane = tid & 63, lr = lane & 15, lk = lane >> 4;
  int br = w >> 2, wq = w & 3;
  int flag = *flagp;
  const float4v Z4 = {0.f,0.f,0.f,0.f};

  const ushort* kb = (br ? kmb16 : khb16) + (size_t)b*32768;
  const ushort* vt = (br ? vtm16 : vth16) + (size_t)b*65536;
  const ushort* qp = qb16 + (size_t)b*32768;
  ushort* esb = es + br*4352;

  for (int idx = tid; idx < 1024; idx += 512){
    int ch = idx >> 4, pp = idx & 15;
    ml[ch*17+pp] = mst[((size_t)b*64 + ch)*1024 + n0 + pp];
  }

  short8v qf = ldfrag(qp + (size_t)(n0 + lr)*32 + lk*8);

  float4v acc[2];
  acc[0]=Z4; acc[1]=Z4;
  float rsum = 0.f;

  #pragma unroll 1
  for (int mc = 0; mc < 4; ++mc){
    int mbase = mc*256 + wq*64;
    #pragma unroll
    for (int tau = 0; tau < 4; ++tau){
      short8v af = ldfrag(kb + (size_t)(mbase + tau*16 + lr)*32 + lk*8);
      float4v d = __builtin_amdgcn_mfma_f32_16x16x32_bf16(af, qf, Z4, 0,0,0);
      ushort u0 = f2bu(__expf(fminf(d[0], 60.f)));
      ushort u1 = f2bu(__expf(fminf(d[1], 60.f)));
      ushort u2 = f2bu(__expf(fminf(d[2], 60.f)));
      ushort u3 = f2bu(__expf(fminf(d[3], 60.f)));
      rsum += (bu2f(u0) + bu2f(u1)) + (bu2f(u2) + bu2f(u3));
      unsigned lo = (unsigned)u0 | ((unsigned)u1 << 16);
      unsigned hi = (unsigned)u2 | ((unsigned)u3 << 16);
      *reinterpret_cast<uint2*>(&esb[lr*272 + wq*64 + tau*16 + lk*4]) = make_uint2(lo, hi);
    }
    __syncthreads();
    #pragma unroll
    for (int ks = 0; ks < 8; ++ks){
      short8v av = ldfrag(vt + (size_t)(wq*16 + lr)*1024 + mc*256 + ks*32 + lk*8);
      short8v bv = ldfrag(&esb[lr*272 + ks*32 + lk*8]);
      acc[ks & 1] = __builtin_amdgcn_mfma_f32_16x16x32_bf16(av, bv, acc[ks & 1], 0,0,0);
    }
    __syncthreads();
  }

  {
    float r = rsum;
    r += __shfl_xor(r, 16);
    r += __shfl_xor(r, 32);
    if (lane < 16) rs_s[br][wq][lr] = r;
  }
  __syncthreads();
  {
    float rinv = 1.0f / (rs_s[br][0][lr] + rs_s[br][1][lr] + rs_s[br][2][lr] + rs_s[br][3][lr]);
    int ch0 = br*64 + wq*16 + lk*4;
    ushort uh[4], ul[4];
    #pragma unroll
    for (int r = 0; r < 4; ++r){
      float z = (acc[0][r] + acc[1][r])*rinv;
      uh[r] = f2bu(z);
      ul[r] = f2bu(z - bu2f(uh[r]));
    }
    *reinterpret_cast<uint2*>(&zbh[lr*136 + ch0]) =
      make_uint2((unsigned)uh[0] | ((unsigned)uh[1]<<16), (unsigned)uh[2] | ((unsigned)uh[3]<<16));
    *reinterpret_cast<uint2*>(&zbl[lr*136 + ch0]) =
      make_uint2((unsigned)ul[0] | ((unsigned)ul[1]<<16), (unsigned)ul[2] | ((unsigned)ul[3]<<16));
  }
  __syncthreads();

  // ---------------- GEMM1: zt = z_w @ z + z_b ----------------
  {
    float4v zacc = Z4;
    if (!flag){
      #pragma unroll
      for (int kf = 0; kf < 4; ++kf){
        short8v a  = ldfrag(zw16h + (size_t)(w*16 + lr)*128 + kf*32 + lk*8);
        short8v bh = ldfrag(&zbh[lr*136 + kf*32 + lk*8]);
        short8v bl = ldfrag(&zbl[lr*136 + kf*32 + lk*8]);
        zacc = __builtin_amdgcn_mfma_f32_16x16x32_bf16(a, bh, zacc, 0,0,0);
        zacc = __builtin_amdgcn_mfma_f32_16x16x32_bf16(a, bl, zacc, 0,0,0);
      }
    } else {
      #pragma unroll
      for (int kf = 0; kf < 4; ++kf){
        short8v a  = ldfrag(zw16h + (size_t)(w*16 + lr)*128 + kf*32 + lk*8);
        short8v al = ldfrag(zw16l + (size_t)(w*16 + lr)*128 + kf*32 + lk*8);
        short8v bh = ldfrag(&zbh[lr*136 + kf*32 + lk*8]);
        short8v bl = ldfrag(&zbl[lr*136 + kf*32 + lk*8]);
        zacc = __builtin_amdgcn_mfma_f32_16x16x32_bf16(a,  bh, zacc, 0,0,0);
        zacc = __builtin_amdgcn_mfma_f32_16x16x32_bf16(a,  bl, zacc, 0,0,0);
        zacc = __builtin_amdgcn_mfma_f32_16x16x32_bf16(al, bh, zacc, 0,0,0);
      }
    }
    int r0 = w*16 + lk*4;
    ushort th[4], tl[4];
    #pragma unroll
    for (int q = 0; q < 4; ++q){
      float ztv = zacc[q] + smalls[O_ZB + r0 + q];
      th[q] = f2bu(ztv);
      tl[q] = f2bu(ztv - bu2f(th[q]));
    }
    *reinterpret_cast<uint2*>(&ztbh[lr*136 + r0]) =
      make_uint2((unsigned)th[0] | ((unsigned)th[1]<<16), (unsigned)th[2] | ((unsigned)th[3]<<16));
    *reinterpret_cast<uint2*>(&ztbl[lr*136 + r0]) =
      make_uint2((unsigned)tl[0] | ((unsigned)tl[1]<<16), (unsigned)tl[2] | ((unsigned)tl[3]<<16));
  }
  __syncthreads();

  // ------- GEMM2: comb = m_w @ [zt; h] + m_b -------
  const ushort* hrow  = hnth + ((size_t)b*1024 + n0 + lr)*64;
  const ushort* hrowl = hntl + ((size_t)b*1024 + n0 + lr)*64;
  #pragma unroll
  for (int mi = 0; mi < 2; ++mi){
    if (mi == 1 && w >= 4) break;
    int mf = (mi == 0) ? w : (w + 8);
    float4v cacc = Z4;
    const ushort* arow  = mw16h + (size_t)(mf*16 + lr)*192;
    const ushort* arowl = mw16l + (size_t)(mf*16 + lr)*192;
    if (!flag){
      #pragma unroll
      for (int kf = 0; kf < 4; ++kf){
        short8v a  = ldfrag(arow + kf*32 + lk*8);
        short8v bh = ldfrag(&ztbh[lr*136 + kf*32 + lk*8]);
        short8v bl = ldfrag(&ztbl[lr*136 + kf*32 + lk*8]);
        cacc = __builtin_amdgcn_mfma_f32_16x16x32_bf16(a, bh, cacc, 0,0,0);
        cacc = __builtin_amdgcn_mfma_f32_16x16x32_bf16(a, bl, cacc, 0,0,0);
      }
      #pragma unroll
      for (int kf = 0; kf < 2; ++kf){
        short8v a  = ldfrag(arow + 128 + kf*32 + lk*8);
        short8v bh = ldfrag(hrow + kf*32 + lk*8);
        short8v bl = ldfrag(hrowl + kf*32 + lk*8);
        cacc = __builtin_amdgcn_mfma_f32_16x16x32_bf16(a, bh, cacc, 0,0,0);
        cacc = __builtin_amdgcn_mfma_f32_16x16x32_bf16(a, bl, cacc, 0,0,0);
      }
    } else {
      #pragma unroll
      for (int kf = 0; kf < 4; ++kf){
        short8v a  = ldfrag(arow + kf*32 + lk*8);
        short8v al = ldfrag(arowl + kf*32 + lk*8);
        short8v bh = ldfrag(&ztbh[lr*136 + kf*32 + lk*8]);
        short8v bl = ldfrag(&ztbl[lr*136 + kf*32 + lk*8]);
        cacc = __builtin_amdgcn_mfma_f32_16x16x32_bf16(a,  bh, cacc, 0,0,0);
        cacc = __builtin_amdgcn_mfma_f32_16x16x32_bf16(a,  bl, cacc, 0,0,0);
        cacc = __builtin_amdgcn_mfma_f32_16x16x32_bf16(al, bh, cacc, 0,0,0);
      }
      #pragma unroll
      for (int kf = 0; kf < 2; ++kf){
        short8v a  = ldfrag(arow + 128 + kf*32 + lk*8);
        short8v al = ldfrag(arowl + 128 + kf*32 + lk*8);
        short8v bh = ldfrag(hrow + kf*32 + lk*8);
        short8v bl = ldfrag(hrowl + kf*32 + lk*8);
        cacc = __builtin_amdgcn_mfma_f32_16x16x32_bf16(a,  bh, cacc, 0,0,0);
        cacc = __builtin_amdgcn_mfma_f32_16x16x32_bf16(a,  bl, cacc, 0,0,0);
        cacc = __builtin_amdgcn_mfma_f32_16x16x32_bf16(al, bh, cacc, 0,0,0);
      }
    }
    int r0 = mf*16 + lk*4;
    #pragma unroll
    for (int q = 0; q < 4; ++q)
      cb[(r0+q)*17 + lr] = cacc[q] + smalls[O_MB + r0 + q];
  }
  __syncthreads();

  // ---------------- gating ----------------
  {
    int px = tid >> 5, lr2 = tid & 31;
    #pragma unroll
    for (int j = 0; j < 2; ++j){
      int ch = lr2 + 32*j;
      float mo = cb[ch*17 + px];
      float mg = cb[(64+ch)*17 + px];
      float mi = cb[(128+ch)*17 + px];
      float mold = ml[ch*17 + px];
      float gi = sigm(mi);
      float mnew = (1.0f-gi)*mold + gi*tanhc(mg);
      float ho = sigm(mo)*mnew;
      ho_s[ch*17+px] = ho;
      mn_s[ch*17+px] = mnew;
    }
  }
  __syncthreads();
  for (int idx = tid; idx < 1024; idx += 512){
    int ch = idx >> 4, pp = idx & 15;
    int n = n0 + pp;
    size_t gidx = ((size_t)b*64 + ch)*1024 + n;
    float mn = mn_s[ch*17+pp];
    mst[gidx] = mn;
    float ho = ho_s[ch*17+pp];
    size_t tix = ((size_t)b*1024 + n)*64 + ch;
    ushort hb_ = f2bu(ho);
    hth[tix] = hb_;
    htl[tix] = f2bu(ho - bu2f(hb_));
    ushort mh_ = f2bu(mn);
    mth[tix] = mh_;
    mtl[tix] = f2bu(mn - bu2f(mh_));
    size_t oidx = ((size_t)(b*64+ch)*8 + t)*1024 + n;
    if (flag) ((float*)outraw)[oidx] = ho;
    else      ((bf16*)outraw)[oidx] = __float2bfloat16(ho);
  }
}

extern "C" void kernel_launch(void* const* d_in, const int* in_sizes, int n_in,
                              void* d_out, int out_size, void* d_ws, size_t ws_size,
                              hipStream_t stream)
{
  float* ws = (float*)d_ws;
  int* flag = (int*)(ws + WS_FLAG);
  float* c    = ws + WS_C;
  float* m    = ws + WS_M;
  ushort* qb16  = (ushort*)(ws + WS_QB16);
  ushort* khb16 = (ushort*)(ws + WS_KHB16);
  ushort* kmb16 = (ushort*)(ws + WS_KMB16);
  ushort* vth16 = (ushort*)(ws + WS_VTH16);
  ushort* vtm16 = (ushort*)(ws + WS_VTM16);
  ushort* mth   = (ushort*)(ws + WS_MTH);
  ushort* mtl   = (ushort*)(ws + WS_MTL);
  ushort* hnth  = (ushort*)(ws + WS_HNTH);
  ushort* hntl  = (ushort*)(ws + WS_HNTL);
  ushort* zw16h = (ushort*)(ws + WS_ZW16H);
  ushort* zw16l = (ushort*)(ws + WS_ZW16L);
  ushort* mw16h = (ushort*)(ws + WS_MW16H);
  ushort* mw16l = (ushort*)(ws + WS_MW16L);
  ushort* wa_hi = (ushort*)(ws + WS_WAHI);
  ushort* wa_lo = (ushort*)(ws + WS_WALO);
  ushort* xt_hi = (ushort*)(ws + WS_XTHI);
  ushort* xt_lo = (ushort*)(ws + WS_XTLO);
  ushort* ht_hi = (ushort*)(ws + WS_HTHI);
  ushort* ht_lo = (ushort*)(ws + WS_HTLO);
  ushort* pwh   = (ushort*)(ws + WS_PWH);
  ushort* pwl   = (ushort*)(ws + WS_PWL);

  k_probe<<<1, 256, 0, stream>>>((const unsigned int*)d_in[0], flag);
  P18 pk;
  for (int i = 0; i < 18; ++i) pk.p[i] = d_in[2 + i];
  k_wconv<<<dim3(64,18), 256, 0, stream>>>(pk, flag, ws);
  k_init<<<3072, 256, 0, stream>>>(d_in[1], flag, ws);
  k_xt<<<dim3(16,32), 256, 0, stream>>>(d_in[0], flag, ws);
  k_wtrans<<<144, 256, 0, stream>>>(ws);

  for (int t = 0; t < 8; ++t){
    k_conv_mfma<<<dim3(64,2,4), 512, 0, stream>>>(flag, wa_hi, wa_lo, xt_hi, xt_lo,
                                                  ht_hi, ht_lo, ws, c, hnth, hntl, t);
    k_projm<<<dim3(64,4), 256, 0, stream>>>(hnth, hntl, mth, mtl, pwh, pwl, ws, flag,
                                            qb16, khb16, kmb16, vth16, vtm16);
    k_fattz<<<dim3(64,4), 512, 0, stream>>>(qb16, khb16, kmb16, vth16, vtm16,
                                            hnth, hntl, ws, zw16h, zw16l, mw16h, mw16l,
                                            flag, m, mth, mtl, ht_hi, ht_lo, d_out, t);
  }
  (void)in_sizes; (void)n_in; (void)out_size; (void)ws_size;
}